// Round 6
// baseline (152.251 us; speedup 1.0000x reference)
//
#include <hip/hip_runtime.h>
#include <hip/hip_bf16.h>
#include <math.h>

#define B_   16
#define C_   512
#define D_   256
#define K_   16
#define RD_  128
#define H_   8
#define HD_  32
#define FFN_ 1024
#define M_   (B_ * C_)   // 8192 rows

typedef __attribute__((ext_vector_type(8))) short bf16x8;
typedef __attribute__((ext_vector_type(4))) float f32x4;

typedef __attribute__((address_space(1))) const int ga_int;
typedef __attribute__((address_space(3))) int ls_int;

static __device__ __forceinline__ short f2bf(float v) {
    __hip_bfloat16 h = __float2bfloat16(v);
    return *(short*)&h;
}

// ---------------------------------------------------------------------------
// All fp32->bf16 conversions in ONE kernel.
// ---------------------------------------------------------------------------
#define N8_X    (M_ * D_ / 8)
#define N8_INW  (768 * D_ / 8)
#define N8_OUTW (D_ * D_ / 8)
#define N8_W1   (FFN_ * D_ / 8)
#define N8_W2   (D_ * FFN_ / 8)
#define N8_TOT  (N8_X + N8_INW + N8_OUTW + N8_W1 + N8_W2)

__global__ __launch_bounds__(256) void convert_all_kernel(
    const float* __restrict__ x, const float* __restrict__ inw,
    const float* __restrict__ outw, const float* __restrict__ w1,
    const float* __restrict__ w2,
    short* __restrict__ xbf, short* __restrict__ inwbf,
    short* __restrict__ outwbf, short* __restrict__ w1bf,
    short* __restrict__ w2bf)
{
    int i = blockIdx.x * 256 + threadIdx.x;
    const float* s; short* d; int off;
    if      (i < N8_X)                          { s = x;    d = xbf;    off = i; }
    else if (i < N8_X + N8_INW)                 { s = inw;  d = inwbf;  off = i - N8_X; }
    else if (i < N8_X + N8_INW + N8_OUTW)       { s = outw; d = outwbf; off = i - N8_X - N8_INW; }
    else if (i < N8_X + N8_INW + N8_OUTW + N8_W1){ s = w1;  d = w1bf;   off = i - N8_X - N8_INW - N8_OUTW; }
    else if (i < N8_TOT)                        { s = w2;   d = w2bf;   off = i - N8_X - N8_INW - N8_OUTW - N8_W1; }
    else return;
    const float4* sp = (const float4*)s + (size_t)off * 2;
    float4 v0 = sp[0], v1 = sp[1];
    short r[8];
    r[0]=f2bf(v0.x); r[1]=f2bf(v0.y); r[2]=f2bf(v0.z); r[3]=f2bf(v0.w);
    r[4]=f2bf(v1.x); r[5]=f2bf(v1.y); r[6]=f2bf(v1.z); r[7]=f2bf(v1.w);
    *(bf16x8*)(d + (size_t)off * 8) = *(bf16x8*)r;
}

// ---------------------------------------------------------------------------
// bf16 MFMA GEMM: C[M,N] = A[M,Kd] @ W[N,Kd]^T + bias (+exact GELU).
// Template BM/BN; 256 threads = 4 waves in 2x2, each (BM/2)x(BN/2).
// Staging via global_load_lds (16B per lane, wave-uniform LDS base).
// ---------------------------------------------------------------------------
template<int BM, int BN, int OUT_BF16, int ACT>
__global__ __launch_bounds__(256) void gemm_mfma(
    const short* __restrict__ A, const short* __restrict__ W,
    const float* __restrict__ bias, void* __restrict__ Cout,
    int M, int N, int Kd)
{
    __shared__ short As[BM * 32];
    __shared__ short Bs[BN * 32];
    const int tid  = threadIdx.x;
    const int wave = tid >> 6;
    const int lane = tid & 63;
    const int bm = blockIdx.y * BM;
    const int bn = blockIdx.x * BN;
    constexpr int MI = BM / 32;
    constexpr int NJ = BN / 32;
    const int wr = (wave >> 1) * (BM / 2);
    const int wc = (wave & 1) * (BN / 2);

    const int fr = lane & 15;          // fragment row within 16
    const int fk = (lane >> 4) * 8;    // fragment k offset (shorts)

    const int r0 = tid >> 2, ch = (tid & 3) * 8;   // staging row / chunk

    f32x4 acc[MI][NJ];
    #pragma unroll
    for (int i = 0; i < MI; ++i)
        #pragma unroll
        for (int j = 0; j < NJ; ++j)
            acc[i][j] = (f32x4){0.f, 0.f, 0.f, 0.f};

    for (int k0 = 0; k0 < Kd; k0 += 32) {
        #pragma unroll
        for (int i = 0; i < BM / 64; ++i)
            __builtin_amdgcn_global_load_lds(
                (ga_int*)&A[(size_t)(bm + r0 + i * 64) * Kd + k0 + ch],
                (ls_int*)&As[(tid + i * 256) * 8], 16, 0, 0);
        #pragma unroll
        for (int j = 0; j < BN / 64; ++j)
            __builtin_amdgcn_global_load_lds(
                (ga_int*)&W[(size_t)(bn + r0 + j * 64) * Kd + k0 + ch],
                (ls_int*)&Bs[(tid + j * 256) * 8], 16, 0, 0);
        __syncthreads();

        bf16x8 af[MI], bfr[NJ];
        #pragma unroll
        for (int i = 0; i < MI; ++i) af[i]  = *(bf16x8*)&As[(wr + i * 16 + fr) * 32 + fk];
        #pragma unroll
        for (int j = 0; j < NJ; ++j) bfr[j] = *(bf16x8*)&Bs[(wc + j * 16 + fr) * 32 + fk];
        #pragma unroll
        for (int i = 0; i < MI; ++i)
            #pragma unroll
            for (int j = 0; j < NJ; ++j)
                acc[i][j] = __builtin_amdgcn_mfma_f32_16x16x32_bf16(af[i], bfr[j], acc[i][j], 0, 0, 0);
        __syncthreads();
    }

    const int rowbase = (lane >> 4) * 4;
    #pragma unroll
    for (int i = 0; i < MI; ++i) {
        #pragma unroll
        for (int j = 0; j < NJ; ++j) {
            const int n = bn + wc + j * 16 + fr;
            const float bn_v = bias ? bias[n] : 0.f;
            #pragma unroll
            for (int r = 0; r < 4; ++r) {
                const int m = bm + wr + i * 16 + rowbase + r;
                float v = acc[i][j][r] + bn_v;
                if (ACT) v = 0.5f * v * (1.0f + erff(v * 0.70710678118654752f));
                if (OUT_BF16) ((short*)Cout)[(size_t)m * N + n] = f2bf(v);
                else          ((float*)Cout)[(size_t)m * N + n] = v;
            }
        }
    }
}

// ---------------------------------------------------------------------------
// Fused xq/xk fp32 GEMM (exact, feeds top-k). blockIdx.z: 0 -> xq, 1 -> xk.
// 64x128 tile, BK=16, 4x8 micro-tile (same kk accumulation order as before
// -> bit-identical outputs -> selection stability).
// ---------------------------------------------------------------------------
__global__ __launch_bounds__(256) void xqk_gemm(
    const float* __restrict__ x, const float* __restrict__ wq,
    const float* __restrict__ wk, float* __restrict__ xqo,
    float* __restrict__ xko)
{
    __shared__ float As[16 * 68];    // [kk][row], pad to 68 (16B-aligned rows)
    __shared__ float Ws[16 * 132];   // [kk][col], pad to 132
    const float* Wm = blockIdx.z ? wk : wq;
    float* Cm       = blockIdx.z ? xko : xqo;

    const int tid = threadIdx.x;
    const int tx = tid & 15;         // col group (x8)
    const int ty = tid >> 4;         // row group (x4)
    const int bm = blockIdx.y * 64;

    const int ra = tid >> 2, qa = (tid & 3) * 4;   // A staging: 256 f4
    float acc[4][8] = {};

    for (int k0 = 0; k0 < D_; k0 += 16) {
        {
            float4 v = *(const float4*)&x[(size_t)(bm + ra) * D_ + k0 + qa];
            As[(qa + 0) * 68 + ra] = v.x;
            As[(qa + 1) * 68 + ra] = v.y;
            As[(qa + 2) * 68 + ra] = v.z;
            As[(qa + 3) * 68 + ra] = v.w;
        }
        #pragma unroll
        for (int e = 0; e < 2; ++e) {
            int t = tid + e * 256;
            int r = t >> 2, q = (t & 3) * 4;
            float4 v = *(const float4*)&Wm[(size_t)r * D_ + k0 + q];
            Ws[(q + 0) * 132 + r] = v.x;
            Ws[(q + 1) * 132 + r] = v.y;
            Ws[(q + 2) * 132 + r] = v.z;
            Ws[(q + 3) * 132 + r] = v.w;
        }
        __syncthreads();
        #pragma unroll
        for (int kk = 0; kk < 16; ++kk) {
            float4 a  = *(const float4*)&As[kk * 68 + ty * 4];
            float4 w0 = *(const float4*)&Ws[kk * 132 + tx * 8];
            float4 w1 = *(const float4*)&Ws[kk * 132 + tx * 8 + 4];
            float av[4] = {a.x, a.y, a.z, a.w};
            float wv[8] = {w0.x, w0.y, w0.z, w0.w, w1.x, w1.y, w1.z, w1.w};
            #pragma unroll
            for (int i = 0; i < 4; ++i)
                #pragma unroll
                for (int j = 0; j < 8; ++j)
                    acc[i][j] += av[i] * wv[j];
        }
        __syncthreads();
    }

    #pragma unroll
    for (int i = 0; i < 4; ++i)
        #pragma unroll
        for (int j = 0; j < 8; ++j)
            Cm[(size_t)(bm + ty * 4 + i) * RD_ + tx * 8 + j] = acc[i][j];
}

// ---------------------------------------------------------------------------
// Batched logits GEMM (fp32, exact): logits[b,q,c] = xq[b,q,:] . xk[b,c,:]
// 128x128 tile, BK=16, 8x8 micro-tile. Same kk order -> bit-identical.
// ---------------------------------------------------------------------------
__global__ __launch_bounds__(256) void logits_gemm(
    const float* __restrict__ xq, const float* __restrict__ xk,
    float* __restrict__ out)
{
    __shared__ float As[16 * 132];
    __shared__ float Ws[16 * 132];
    const int tid = threadIdx.x;
    const int tx = tid & 15;
    const int ty = tid >> 4;
    const int bm = blockIdx.y * 128;
    const int bn = blockIdx.x * 128;
    const int b  = blockIdx.z;

    const float* A = xq + (size_t)b * C_ * RD_;
    const float* W = xk + (size_t)b * C_ * RD_;
    float* Cmat    = out + (size_t)b * C_ * C_;

    float acc[8][8] = {};

    for (int k0 = 0; k0 < RD_; k0 += 16) {
        #pragma unroll
        for (int e = 0; e < 2; ++e) {
            int t = tid + e * 256;
            int r = t >> 2, q = (t & 3) * 4;
            float4 va = *(const float4*)&A[(size_t)(bm + r) * RD_ + k0 + q];
            As[(q + 0) * 132 + r] = va.x;
            As[(q + 1) * 132 + r] = va.y;
            As[(q + 2) * 132 + r] = va.z;
            As[(q + 3) * 132 + r] = va.w;
            float4 vw = *(const float4*)&W[(size_t)(bn + r) * RD_ + k0 + q];
            Ws[(q + 0) * 132 + r] = vw.x;
            Ws[(q + 1) * 132 + r] = vw.y;
            Ws[(q + 2) * 132 + r] = vw.z;
            Ws[(q + 3) * 132 + r] = vw.w;
        }
        __syncthreads();
        #pragma unroll
        for (int kk = 0; kk < 16; ++kk) {
            float4 a0 = *(const float4*)&As[kk * 132 + ty * 8];
            float4 a1 = *(const float4*)&As[kk * 132 + ty * 8 + 4];
            float4 w0 = *(const float4*)&Ws[kk * 132 + tx * 8];
            float4 w1 = *(const float4*)&Ws[kk * 132 + tx * 8 + 4];
            float av[8] = {a0.x, a0.y, a0.z, a0.w, a1.x, a1.y, a1.z, a1.w};
            float wv[8] = {w0.x, w0.y, w0.z, w0.w, w1.x, w1.y, w1.z, w1.w};
            #pragma unroll
            for (int i = 0; i < 8; ++i)
                #pragma unroll
                for (int j = 0; j < 8; ++j)
                    acc[i][j] += av[i] * wv[j];
        }
        __syncthreads();
    }

    #pragma unroll
    for (int i = 0; i < 8; ++i)
        #pragma unroll
        for (int j = 0; j < 8; ++j)
            Cmat[(size_t)(bm + ty * 8 + i) * C_ + bn + tx * 8 + j] = acc[i][j];
}

// ---------------------------------------------------------------------------
// FUSED top-16 + attention, ONE WAVE per (b,q) row, zero barriers.
// ---------------------------------------------------------------------------
__global__ __launch_bounds__(256) void topk_attn_kernel(
    const float* __restrict__ logits, const float* __restrict__ qkv,
    short* __restrict__ ctxbf)
{
    const int wave = threadIdx.x >> 6;
    const int lane = threadIdx.x & 63;
    const int row  = blockIdx.x * 4 + wave;        // global (b*C + q)
    const int bbase = row & ~(C_ - 1);             // batch base row

    // ---- top-16 ----
    const float* lrow = logits + (size_t)row * C_;
    unsigned long long key[8];
    #pragma unroll
    for (int j = 0; j < 8; ++j) {
        int pos = lane * 8 + j;
        unsigned u = __float_as_uint(lrow[pos]);
        u = (u & 0x80000000u) ? ~u : (u | 0x80000000u);
        key[j] = (((unsigned long long)u) << 9) | (unsigned)(511 - pos);
    }

    int ii[K_];
    #pragma unroll
    for (int sel = 0; sel < K_; ++sel) {
        unsigned long long best = key[0];
        #pragma unroll
        for (int j = 1; j < 8; ++j) best = key[j] > best ? key[j] : best;
        #pragma unroll
        for (int s = 1; s < 64; s <<= 1) {
            unsigned long long o = __shfl_xor(best, s, 64);
            best = o > best ? o : best;
        }
        int pos = 511 - (int)(best & 511ull);      // wave-uniform
        ii[sel] = pos;
        if ((pos >> 3) == lane) key[pos & 7] = 0ull;
    }

    // ---- attention over the 16 selected slots ----
    const float* qrow = qkv + (size_t)row * 768;
    float4 qv = *(const float4*)(qrow + lane * 4);

    float s[K_];
    #pragma unroll
    for (int k = 0; k < K_; ++k) {
        const float* kr = qkv + (size_t)(bbase + ii[k]) * 768 + 256;
        float4 kv = *(const float4*)(kr + lane * 4);
        float p = qv.x * kv.x + qv.y * kv.y + qv.z * kv.z + qv.w * kv.w;
        p += __shfl_xor(p, 1, 64);
        p += __shfl_xor(p, 2, 64);
        p += __shfl_xor(p, 4, 64);
        s[k] = p * 0.17677669529663687f;
    }

    float m = s[0];
    #pragma unroll
    for (int k = 1; k < K_; ++k) m = fmaxf(m, s[k]);
    float ssum = 0.f;
    #pragma unroll
    for (int k = 0; k < K_; ++k) { s[k] = __expf(s[k] - m); ssum += s[k]; }
    const float inv = 1.f / ssum;

    float4 acc = {0.f, 0.f, 0.f, 0.f};
    #pragma unroll
    for (int k = 0; k < K_; ++k) {
        const float* vr = qkv + (size_t)(bbase + ii[k]) * 768 + 512;
        float4 vv = *(const float4*)(vr + lane * 4);
        float w = s[k] * inv;
        acc.x += w * vv.x; acc.y += w * vv.y; acc.z += w * vv.z; acc.w += w * vv.w;
    }

    unsigned lo = (unsigned)(unsigned short)f2bf(acc.x) | ((unsigned)(unsigned short)f2bf(acc.y) << 16);
    unsigned hi = (unsigned)(unsigned short)f2bf(acc.z) | ((unsigned)(unsigned short)f2bf(acc.w) << 16);
    uint2 pk = {lo, hi};
    *(uint2*)(ctxbf + (size_t)row * D_ + lane * 4) = pk;
}

// ---------------------------------------------------------------------------
// out = LN(a + res), ONE WAVE per row (shuffle reductions, no barriers).
// ---------------------------------------------------------------------------
template<int WBF>
__global__ __launch_bounds__(256) void add_ln_wave_kernel(
    const float* __restrict__ a, const float* __restrict__ res,
    const float* __restrict__ g, const float* __restrict__ beta,
    float* __restrict__ out, short* __restrict__ outbf)
{
    const int wave = threadIdx.x >> 6;
    const int lane = threadIdx.x & 63;
    const int row  = blockIdx.x * 4 + wave;

    float4 va = *(const float4*)(a   + (size_t)row * D_ + lane * 4);
    float4 vr = *(const float4*)(res + (size_t)row * D_ + lane * 4);
    float4 v = {va.x + vr.x, va.y + vr.y, va.z + vr.z, va.w + vr.w};

    float t = v.x + v.y + v.z + v.w;
    #pragma unroll
    for (int s = 1; s < 64; s <<= 1) t += __shfl_xor(t, s, 64);
    const float mean = t * (1.0f / D_);

    float4 dv = {v.x - mean, v.y - mean, v.z - mean, v.w - mean};
    float sq = dv.x * dv.x + dv.y * dv.y + dv.z * dv.z + dv.w * dv.w;
    #pragma unroll
    for (int s = 1; s < 64; s <<= 1) sq += __shfl_xor(sq, s, 64);
    const float rstd = rsqrtf(sq * (1.0f / D_) + 1e-5f);

    float4 gv = *(const float4*)(g    + lane * 4);
    float4 bv = *(const float4*)(beta + lane * 4);
    float4 o = {dv.x * rstd * gv.x + bv.x, dv.y * rstd * gv.y + bv.y,
                dv.z * rstd * gv.z + bv.z, dv.w * rstd * gv.w + bv.w};
    *(float4*)(out + (size_t)row * D_ + lane * 4) = o;
    if (WBF) {
        unsigned lo = (unsigned)(unsigned short)f2bf(o.x) | ((unsigned)(unsigned short)f2bf(o.y) << 16);
        unsigned hi = (unsigned)(unsigned short)f2bf(o.z) | ((unsigned)(unsigned short)f2bf(o.w) << 16);
        uint2 pk = {lo, hi};
        *(uint2*)(outbf + (size_t)row * D_ + lane * 4) = pk;
    }
}

// ---------------------------------------------------------------------------
extern "C" void kernel_launch(void* const* d_in, const int* in_sizes, int n_in,
                              void* d_out, int out_size, void* d_ws, size_t ws_size,
                              hipStream_t stream)
{
    const float* x      = (const float*)d_in[0];
    const float* wq_rec = (const float*)d_in[1];
    const float* wk_rec = (const float*)d_in[2];
    const float* in_w   = (const float*)d_in[3];
    const float* in_b   = (const float*)d_in[4];
    const float* out_w  = (const float*)d_in[5];
    const float* out_b  = (const float*)d_in[6];
    const float* ln1_g  = (const float*)d_in[7];
    const float* ln1_b  = (const float*)d_in[8];
    const float* w1     = (const float*)d_in[9];
    const float* b1     = (const float*)d_in[10];
    const float* w2     = (const float*)d_in[11];
    const float* b2     = (const float*)d_in[12];
    const float* ln2_g  = (const float*)d_in[13];
    const float* ln2_b  = (const float*)d_in[14];
    float* out = (float*)d_out;

    // ---- workspace layout (floats) ----
    float* ws = (float*)d_ws;
    float* qkv   = ws;                              // M*768 f
    float* xq    = qkv + (size_t)M_ * 768;          // M*128 f
    float* xk    = xq  + (size_t)M_ * RD_;          // M*128 f
    float* x1    = xk  + (size_t)M_ * RD_;          // M*256 f
    float* ao    = x1 + (size_t)M_ * D_;            // M*256 f
    float* U     = ao + (size_t)M_ * D_;            // union region
    float* logits = U;                                  // M*512 f      (topk phase)
    short* ctxbf  = (short*)U;                          // M*256 bf16   (attn->outproj)
    short* x1bf   = (short*)U + (size_t)M_ * D_;        // M*256 bf16   (ln1->mlp1)
    short* hbf    = (short*)U + (size_t)2 * M_ * D_;    // M*1024 bf16  (mlp1->mlp2)
    float* afterU = U + (size_t)3 * M_ * D_;
    short* xbf    = (short*)afterU;                     // M*256 bf16
    short* inwbf  = xbf   + (size_t)M_ * D_;
    short* outwbf = inwbf + (size_t)768 * D_;
    short* w1bf   = outwbf + (size_t)D_ * D_;
    short* w2bf   = w1bf  + (size_t)FFN_ * D_;

    dim3 blk(256);

    // 0) all bf16 conversions, one launch
    convert_all_kernel<<<dim3((N8_TOT + 255) / 256), blk, 0, stream>>>(
        x, in_w, out_w, w1, w2, xbf, inwbf, outwbf, w1bf, w2bf);

    // 1) qkv = x @ in_proj_w^T + b  (MFMA, 64x128 -> 768 blocks)
    gemm_mfma<64, 128, 0, 0><<<dim3(768 / 128, M_ / 64), blk, 0, stream>>>(xbf, inwbf, in_b, qkv, M_, 768, D_);
    // 2) xq/xk recurrence projections (fp32 exact), 64x128 tile, 256 blocks
    xqk_gemm<<<dim3(1, M_ / 64, 2), blk, 0, stream>>>(x, wq_rec, wk_rec, xq, xk);
    // 3) logits (fp32 exact), 128x128 tile, 8x8 micro, 256 blocks
    logits_gemm<<<dim3(C_ / 128, C_ / 128, B_), blk, 0, stream>>>(xq, xk, logits);
    // 4) fused top-16 + gathered attention -> ctx (bf16)
    topk_attn_kernel<<<dim3(M_ / 4), blk, 0, stream>>>(logits, qkv, ctxbf);
    // 5) out projection (MFMA, 64x64 -> 512 blocks)
    gemm_mfma<64, 64, 0, 0><<<dim3(D_ / 64, M_ / 64), blk, 0, stream>>>(ctxbf, outwbf, out_b, ao, M_, D_, D_);
    // 6) x1 = LN(attn_out + x), + bf16 copy
    add_ln_wave_kernel<1><<<dim3(M_ / 4), blk, 0, stream>>>(ao, x, ln1_g, ln1_b, x1, x1bf);
    // 7) h = gelu(x1 @ w1^T + b1) (MFMA, 128x128 -> 512 blocks, bf16 out)
    gemm_mfma<128, 128, 1, 1><<<dim3(FFN_ / 128, M_ / 128), blk, 0, stream>>>(x1bf, w1bf, b1, hbf, M_, FFN_, D_);
    // 8) y = h @ w2^T + b2 (MFMA, 64x64 -> 512 blocks)
    gemm_mfma<64, 64, 0, 0><<<dim3(D_ / 64, M_ / 64), blk, 0, stream>>>(hbf, w2bf, b2, ao, M_, D_, FFN_);
    // 9) out = LN(y + x1)
    add_ln_wave_kernel<0><<<dim3(M_ / 4), blk, 0, stream>>>(ao, x1, ln2_g, ln2_b, out, nullptr);
}

// Round 7
// 144.648 us; speedup vs baseline: 1.0526x; 1.0526x over previous
//
#include <hip/hip_runtime.h>
#include <hip/hip_bf16.h>
#include <math.h>

#define B_   16
#define C_   512
#define D_   256
#define K_   16
#define RD_  128
#define H_   8
#define HD_  32
#define FFN_ 1024
#define M_   (B_ * C_)   // 8192 rows

typedef __attribute__((ext_vector_type(8))) short bf16x8;
typedef __attribute__((ext_vector_type(4))) float f32x4;

typedef __attribute__((address_space(1))) const int ga_int;
typedef __attribute__((address_space(3))) int ls_int;

static __device__ __forceinline__ short f2bf(float v) {
    __hip_bfloat16 h = __float2bfloat16(v);
    return *(short*)&h;
}

// ---------------------------------------------------------------------------
// All fp32->bf16 conversions in ONE kernel.
// ---------------------------------------------------------------------------
#define N8_X    (M_ * D_ / 8)
#define N8_INW  (768 * D_ / 8)
#define N8_OUTW (D_ * D_ / 8)
#define N8_W1   (FFN_ * D_ / 8)
#define N8_W2   (D_ * FFN_ / 8)
#define N8_TOT  (N8_X + N8_INW + N8_OUTW + N8_W1 + N8_W2)

__global__ __launch_bounds__(256) void convert_all_kernel(
    const float* __restrict__ x, const float* __restrict__ inw,
    const float* __restrict__ outw, const float* __restrict__ w1,
    const float* __restrict__ w2,
    short* __restrict__ xbf, short* __restrict__ inwbf,
    short* __restrict__ outwbf, short* __restrict__ w1bf,
    short* __restrict__ w2bf)
{
    int i = blockIdx.x * 256 + threadIdx.x;
    const float* s; short* d; int off;
    if      (i < N8_X)                          { s = x;    d = xbf;    off = i; }
    else if (i < N8_X + N8_INW)                 { s = inw;  d = inwbf;  off = i - N8_X; }
    else if (i < N8_X + N8_INW + N8_OUTW)       { s = outw; d = outwbf; off = i - N8_X - N8_INW; }
    else if (i < N8_X + N8_INW + N8_OUTW + N8_W1){ s = w1;  d = w1bf;   off = i - N8_X - N8_INW - N8_OUTW; }
    else if (i < N8_TOT)                        { s = w2;   d = w2bf;   off = i - N8_X - N8_INW - N8_OUTW - N8_W1; }
    else return;
    const float4* sp = (const float4*)s + (size_t)off * 2;
    float4 v0 = sp[0], v1 = sp[1];
    short r[8];
    r[0]=f2bf(v0.x); r[1]=f2bf(v0.y); r[2]=f2bf(v0.z); r[3]=f2bf(v0.w);
    r[4]=f2bf(v1.x); r[5]=f2bf(v1.y); r[6]=f2bf(v1.z); r[7]=f2bf(v1.w);
    *(bf16x8*)(d + (size_t)off * 8) = *(bf16x8*)r;
}

// ---------------------------------------------------------------------------
// bf16 MFMA GEMM: C[M,N] = A[M,Kd] @ W[N,Kd]^T + bias (+exact GELU).
// Template BM/BN; 256 threads = 4 waves in 2x2, each (BM/2)x(BN/2).
// DOUBLE-BUFFERED global_load_lds staging (T3 minimum 2-phase recipe):
// issue tile t+1's loads before computing tile t; one barrier per K-step.
// ---------------------------------------------------------------------------
template<int BM, int BN, int OUT_BF16, int ACT>
__global__ __launch_bounds__(256) void gemm_mfma(
    const short* __restrict__ A, const short* __restrict__ W,
    const float* __restrict__ bias, void* __restrict__ Cout,
    int M, int N, int Kd)
{
    __shared__ short As[2][BM * 32];
    __shared__ short Bs[2][BN * 32];
    const int tid  = threadIdx.x;
    const int wave = tid >> 6;
    const int lane = tid & 63;
    const int bm = blockIdx.y * BM;
    const int bn = blockIdx.x * BN;
    constexpr int MI = BM / 32;
    constexpr int NJ = BN / 32;
    const int wr = (wave >> 1) * (BM / 2);
    const int wc = (wave & 1) * (BN / 2);

    const int fr = lane & 15;          // fragment row within 16
    const int fk = (lane >> 4) * 8;    // fragment k offset (shorts)

    const int r0 = tid >> 2, ch = (tid & 3) * 8;   // staging row / chunk

    f32x4 acc[MI][NJ];
    #pragma unroll
    for (int i = 0; i < MI; ++i)
        #pragma unroll
        for (int j = 0; j < NJ; ++j)
            acc[i][j] = (f32x4){0.f, 0.f, 0.f, 0.f};

    // ---- stage(buf, k0): issue async loads for K-tile k0 into buffer buf
    auto stage = [&](int buf, int k0) {
        #pragma unroll
        for (int i = 0; i < BM / 64; ++i)
            __builtin_amdgcn_global_load_lds(
                (ga_int*)&A[(size_t)(bm + r0 + i * 64) * Kd + k0 + ch],
                (ls_int*)&As[buf][(tid + i * 256) * 8], 16, 0, 0);
        #pragma unroll
        for (int j = 0; j < BN / 64; ++j)
            __builtin_amdgcn_global_load_lds(
                (ga_int*)&W[(size_t)(bn + r0 + j * 64) * Kd + k0 + ch],
                (ls_int*)&Bs[buf][(tid + j * 256) * 8], 16, 0, 0);
    };

    stage(0, 0);
    int cur = 0;

    for (int k0 = 0; k0 < Kd; k0 += 32) {
        __syncthreads();   // drains vmcnt: buf[cur] ready; prev reads of buf[cur^1] done
        if (k0 + 32 < Kd) stage(cur ^ 1, k0 + 32);   // overlap with compute below

        bf16x8 af[MI], bfr[NJ];
        #pragma unroll
        for (int i = 0; i < MI; ++i) af[i]  = *(bf16x8*)&As[cur][(wr + i * 16 + fr) * 32 + fk];
        #pragma unroll
        for (int j = 0; j < NJ; ++j) bfr[j] = *(bf16x8*)&Bs[cur][(wc + j * 16 + fr) * 32 + fk];
        #pragma unroll
        for (int i = 0; i < MI; ++i)
            #pragma unroll
            for (int j = 0; j < NJ; ++j)
                acc[i][j] = __builtin_amdgcn_mfma_f32_16x16x32_bf16(af[i], bfr[j], acc[i][j], 0, 0, 0);
        cur ^= 1;
    }

    const int rowbase = (lane >> 4) * 4;
    #pragma unroll
    for (int i = 0; i < MI; ++i) {
        #pragma unroll
        for (int j = 0; j < NJ; ++j) {
            const int n = bn + wc + j * 16 + fr;
            const float bn_v = bias ? bias[n] : 0.f;
            #pragma unroll
            for (int r = 0; r < 4; ++r) {
                const int m = bm + wr + i * 16 + rowbase + r;
                float v = acc[i][j][r] + bn_v;
                if (ACT) v = 0.5f * v * (1.0f + erff(v * 0.70710678118654752f));
                if (OUT_BF16) ((short*)Cout)[(size_t)m * N + n] = f2bf(v);
                else          ((float*)Cout)[(size_t)m * N + n] = v;
            }
        }
    }
}

// ---------------------------------------------------------------------------
// Fused xq/xk fp32 GEMM (exact, feeds top-k). blockIdx.z: 0 -> xq, 1 -> xk.
// Round-5 configuration: 64x64 tile, 4x4 micro, grid (2, 128, 2) = 512 blocks.
// ---------------------------------------------------------------------------
__global__ __launch_bounds__(256) void xqk_gemm(
    const float* __restrict__ x, const float* __restrict__ wq,
    const float* __restrict__ wk, float* __restrict__ xqo,
    float* __restrict__ xko)
{
    __shared__ float As[16 * 68];
    __shared__ float Ws[16 * 68];
    const float* Wm = blockIdx.z ? wk : wq;
    float* Cm       = blockIdx.z ? xko : xqo;

    const int tid = threadIdx.x;
    const int tx = tid & 15;
    const int ty = tid >> 4;
    const int bm = blockIdx.y * 64;
    const int bn = blockIdx.x * 64;

    float acc[4][4] = {};

    for (int k0 = 0; k0 < D_; k0 += 16) {
        #pragma unroll
        for (int i = 0; i < 4; ++i) {
            int e  = tid + i * 256;
            int r  = e >> 4;
            int kk = e & 15;
            As[kk * 68 + r] = x[(size_t)(bm + r) * D_ + k0 + kk];
            Ws[kk * 68 + r] = Wm[(size_t)(bn + r) * D_ + k0 + kk];
        }
        __syncthreads();
        #pragma unroll
        for (int kk = 0; kk < 16; ++kk) {
            float4 a = *(const float4*)&As[kk * 68 + ty * 4];
            float4 w = *(const float4*)&Ws[kk * 68 + tx * 4];
            float av[4] = {a.x, a.y, a.z, a.w};
            float wv[4] = {w.x, w.y, w.z, w.w};
            #pragma unroll
            for (int i = 0; i < 4; ++i)
                #pragma unroll
                for (int j = 0; j < 4; ++j)
                    acc[i][j] += av[i] * wv[j];
        }
        __syncthreads();
    }

    #pragma unroll
    for (int i = 0; i < 4; ++i)
        #pragma unroll
        for (int j = 0; j < 4; ++j)
            Cm[(size_t)(bm + ty * 4 + i) * RD_ + bn + tx * 4 + j] = acc[i][j];
}

// ---------------------------------------------------------------------------
// Batched logits GEMM (fp32, exact): logits[b,q,c] = xq[b,q,:] . xk[b,c,:]
// Round-5 configuration: 64x64 tile, 4x4 micro, grid (8, 8, 16) = 1024 blocks.
// ---------------------------------------------------------------------------
__global__ __launch_bounds__(256) void logits_gemm(
    const float* __restrict__ xq, const float* __restrict__ xk,
    float* __restrict__ out)
{
    __shared__ float As[16 * 68];
    __shared__ float Ws[16 * 68];
    const int tid = threadIdx.x;
    const int tx = tid & 15;
    const int ty = tid >> 4;
    const int bm = blockIdx.y * 64;
    const int bn = blockIdx.x * 64;
    const int b  = blockIdx.z;

    const float* A = xq + (size_t)b * C_ * RD_;
    const float* W = xk + (size_t)b * C_ * RD_;
    float* Cmat    = out + (size_t)b * C_ * C_;

    float acc[4][4] = {};

    for (int k0 = 0; k0 < RD_; k0 += 16) {
        #pragma unroll
        for (int i = 0; i < 4; ++i) {
            int e  = tid + i * 256;
            int r  = e >> 4;
            int kk = e & 15;
            As[kk * 68 + r] = A[(size_t)(bm + r) * RD_ + k0 + kk];
            Ws[kk * 68 + r] = W[(size_t)(bn + r) * RD_ + k0 + kk];
        }
        __syncthreads();
        #pragma unroll
        for (int kk = 0; kk < 16; ++kk) {
            float4 a = *(const float4*)&As[kk * 68 + ty * 4];
            float4 w = *(const float4*)&Ws[kk * 68 + tx * 4];
            float av[4] = {a.x, a.y, a.z, a.w};
            float wv[4] = {w.x, w.y, w.z, w.w};
            #pragma unroll
            for (int i = 0; i < 4; ++i)
                #pragma unroll
                for (int j = 0; j < 4; ++j)
                    acc[i][j] += av[i] * wv[j];
        }
        __syncthreads();
    }

    #pragma unroll
    for (int i = 0; i < 4; ++i)
        #pragma unroll
        for (int j = 0; j < 4; ++j)
            Cmat[(size_t)(bm + ty * 4 + i) * C_ + bn + tx * 4 + j] = acc[i][j];
}

// ---------------------------------------------------------------------------
// FUSED top-16 + attention, ONE WAVE per (b,q) row, zero barriers.
// ---------------------------------------------------------------------------
__global__ __launch_bounds__(256) void topk_attn_kernel(
    const float* __restrict__ logits, const float* __restrict__ qkv,
    short* __restrict__ ctxbf)
{
    const int wave = threadIdx.x >> 6;
    const int lane = threadIdx.x & 63;
    const int row  = blockIdx.x * 4 + wave;        // global (b*C + q)
    const int bbase = row & ~(C_ - 1);             // batch base row

    // ---- top-16 ----
    const float* lrow = logits + (size_t)row * C_;
    unsigned long long key[8];
    #pragma unroll
    for (int j = 0; j < 8; ++j) {
        int pos = lane * 8 + j;
        unsigned u = __float_as_uint(lrow[pos]);
        u = (u & 0x80000000u) ? ~u : (u | 0x80000000u);
        key[j] = (((unsigned long long)u) << 9) | (unsigned)(511 - pos);
    }

    int ii[K_];
    #pragma unroll
    for (int sel = 0; sel < K_; ++sel) {
        unsigned long long best = key[0];
        #pragma unroll
        for (int j = 1; j < 8; ++j) best = key[j] > best ? key[j] : best;
        #pragma unroll
        for (int s = 1; s < 64; s <<= 1) {
            unsigned long long o = __shfl_xor(best, s, 64);
            best = o > best ? o : best;
        }
        int pos = 511 - (int)(best & 511ull);      // wave-uniform
        ii[sel] = pos;
        if ((pos >> 3) == lane) key[pos & 7] = 0ull;
    }

    // ---- attention over the 16 selected slots ----
    const float* qrow = qkv + (size_t)row * 768;
    float4 qv = *(const float4*)(qrow + lane * 4);

    float s[K_];
    #pragma unroll
    for (int k = 0; k < K_; ++k) {
        const float* kr = qkv + (size_t)(bbase + ii[k]) * 768 + 256;
        float4 kv = *(const float4*)(kr + lane * 4);
        float p = qv.x * kv.x + qv.y * kv.y + qv.z * kv.z + qv.w * kv.w;
        p += __shfl_xor(p, 1, 64);
        p += __shfl_xor(p, 2, 64);
        p += __shfl_xor(p, 4, 64);
        s[k] = p * 0.17677669529663687f;
    }

    float m = s[0];
    #pragma unroll
    for (int k = 1; k < K_; ++k) m = fmaxf(m, s[k]);
    float ssum = 0.f;
    #pragma unroll
    for (int k = 0; k < K_; ++k) { s[k] = __expf(s[k] - m); ssum += s[k]; }
    const float inv = 1.f / ssum;

    float4 acc = {0.f, 0.f, 0.f, 0.f};
    #pragma unroll
    for (int k = 0; k < K_; ++k) {
        const float* vr = qkv + (size_t)(bbase + ii[k]) * 768 + 512;
        float4 vv = *(const float4*)(vr + lane * 4);
        float w = s[k] * inv;
        acc.x += w * vv.x; acc.y += w * vv.y; acc.z += w * vv.z; acc.w += w * vv.w;
    }

    unsigned lo = (unsigned)(unsigned short)f2bf(acc.x) | ((unsigned)(unsigned short)f2bf(acc.y) << 16);
    unsigned hi = (unsigned)(unsigned short)f2bf(acc.z) | ((unsigned)(unsigned short)f2bf(acc.w) << 16);
    uint2 pk = {lo, hi};
    *(uint2*)(ctxbf + (size_t)row * D_ + lane * 4) = pk;
}

// ---------------------------------------------------------------------------
// out = LN(a + res), ONE WAVE per row (shuffle reductions, no barriers).
// ---------------------------------------------------------------------------
template<int WBF>
__global__ __launch_bounds__(256) void add_ln_wave_kernel(
    const float* __restrict__ a, const float* __restrict__ res,
    const float* __restrict__ g, const float* __restrict__ beta,
    float* __restrict__ out, short* __restrict__ outbf)
{
    const int wave = threadIdx.x >> 6;
    const int lane = threadIdx.x & 63;
    const int row  = blockIdx.x * 4 + wave;

    float4 va = *(const float4*)(a   + (size_t)row * D_ + lane * 4);
    float4 vr = *(const float4*)(res + (size_t)row * D_ + lane * 4);
    float4 v = {va.x + vr.x, va.y + vr.y, va.z + vr.z, va.w + vr.w};

    float t = v.x + v.y + v.z + v.w;
    #pragma unroll
    for (int s = 1; s < 64; s <<= 1) t += __shfl_xor(t, s, 64);
    const float mean = t * (1.0f / D_);

    float4 dv = {v.x - mean, v.y - mean, v.z - mean, v.w - mean};
    float sq = dv.x * dv.x + dv.y * dv.y + dv.z * dv.z + dv.w * dv.w;
    #pragma unroll
    for (int s = 1; s < 64; s <<= 1) sq += __shfl_xor(sq, s, 64);
    const float rstd = rsqrtf(sq * (1.0f / D_) + 1e-5f);

    float4 gv = *(const float4*)(g    + lane * 4);
    float4 bv = *(const float4*)(beta + lane * 4);
    float4 o = {dv.x * rstd * gv.x + bv.x, dv.y * rstd * gv.y + bv.y,
                dv.z * rstd * gv.z + bv.z, dv.w * rstd * gv.w + bv.w};
    *(float4*)(out + (size_t)row * D_ + lane * 4) = o;
    if (WBF) {
        unsigned lo = (unsigned)(unsigned short)f2bf(o.x) | ((unsigned)(unsigned short)f2bf(o.y) << 16);
        unsigned hi = (unsigned)(unsigned short)f2bf(o.z) | ((unsigned)(unsigned short)f2bf(o.w) << 16);
        uint2 pk = {lo, hi};
        *(uint2*)(outbf + (size_t)row * D_ + lane * 4) = pk;
    }
}

// ---------------------------------------------------------------------------
extern "C" void kernel_launch(void* const* d_in, const int* in_sizes, int n_in,
                              void* d_out, int out_size, void* d_ws, size_t ws_size,
                              hipStream_t stream)
{
    const float* x      = (const float*)d_in[0];
    const float* wq_rec = (const float*)d_in[1];
    const float* wk_rec = (const float*)d_in[2];
    const float* in_w   = (const float*)d_in[3];
    const float* in_b   = (const float*)d_in[4];
    const float* out_w  = (const float*)d_in[5];
    const float* out_b  = (const float*)d_in[6];
    const float* ln1_g  = (const float*)d_in[7];
    const float* ln1_b  = (const float*)d_in[8];
    const float* w1     = (const float*)d_in[9];
    const float* b1     = (const float*)d_in[10];
    const float* w2     = (const float*)d_in[11];
    const float* b2     = (const float*)d_in[12];
    const float* ln2_g  = (const float*)d_in[13];
    const float* ln2_b  = (const float*)d_in[14];
    float* out = (float*)d_out;

    // ---- workspace layout (floats) ----
    float* ws = (float*)d_ws;
    float* qkv   = ws;                              // M*768 f
    float* xq    = qkv + (size_t)M_ * 768;          // M*128 f
    float* xk    = xq  + (size_t)M_ * RD_;          // M*128 f
    float* x1    = xk  + (size_t)M_ * RD_;          // M*256 f
    float* ao    = x1 + (size_t)M_ * D_;            // M*256 f
    float* U     = ao + (size_t)M_ * D_;            // union region
    float* logits = U;                                  // M*512 f      (topk phase)
    short* ctxbf  = (short*)U;                          // M*256 bf16   (attn->outproj)
    short* x1bf   = (short*)U + (size_t)M_ * D_;        // M*256 bf16   (ln1->mlp1)
    short* hbf    = (short*)U + (size_t)2 * M_ * D_;    // M*1024 bf16  (mlp1->mlp2)
    float* afterU = U + (size_t)3 * M_ * D_;
    short* xbf    = (short*)afterU;                     // M*256 bf16
    short* inwbf  = xbf   + (size_t)M_ * D_;
    short* outwbf = inwbf + (size_t)768 * D_;
    short* w1bf   = outwbf + (size_t)D_ * D_;
    short* w2bf   = w1bf  + (size_t)FFN_ * D_;

    dim3 blk(256);

    // 0) all bf16 conversions, one launch
    convert_all_kernel<<<dim3((N8_TOT + 255) / 256), blk, 0, stream>>>(
        x, in_w, out_w, w1, w2, xbf, inwbf, outwbf, w1bf, w2bf);

    // 1) qkv = x @ in_proj_w^T + b  (MFMA, 64x128 -> 768 blocks)
    gemm_mfma<64, 128, 0, 0><<<dim3(768 / 128, M_ / 64), blk, 0, stream>>>(xbf, inwbf, in_b, qkv, M_, 768, D_);
    // 2) xq/xk recurrence projections (fp32 exact), 64x64 tile, 512 blocks
    xqk_gemm<<<dim3(RD_ / 64, M_ / 64, 2), blk, 0, stream>>>(x, wq_rec, wk_rec, xq, xk);
    // 3) logits (fp32 exact), 64x64 tile, 1024 blocks
    logits_gemm<<<dim3(C_ / 64, C_ / 64, B_), blk, 0, stream>>>(xq, xk, logits);
    // 4) fused top-16 + gathered attention -> ctx (bf16)
    topk_attn_kernel<<<dim3(M_ / 4), blk, 0, stream>>>(logits, qkv, ctxbf);
    // 5) out projection (MFMA, 64x64 -> 512 blocks)
    gemm_mfma<64, 64, 0, 0><<<dim3(D_ / 64, M_ / 64), blk, 0, stream>>>(ctxbf, outwbf, out_b, ao, M_, D_, D_);
    // 6) x1 = LN(attn_out + x), + bf16 copy
    add_ln_wave_kernel<1><<<dim3(M_ / 4), blk, 0, stream>>>(ao, x, ln1_g, ln1_b, x1, x1bf);
    // 7) h = gelu(x1 @ w1^T + b1) (MFMA, 128x128 -> 512 blocks, bf16 out)
    gemm_mfma<128, 128, 1, 1><<<dim3(FFN_ / 128, M_ / 128), blk, 0, stream>>>(x1bf, w1bf, b1, hbf, M_, FFN_, D_);
    // 8) y = h @ w2^T + b2 (MFMA, 64x64 -> 512 blocks)
    gemm_mfma<64, 64, 0, 0><<<dim3(D_ / 64, M_ / 64), blk, 0, stream>>>(hbf, w2bf, b2, ao, M_, D_, FFN_);
    // 9) out = LN(y + x1)
    add_ln_wave_kernel<0><<<dim3(M_ / 4), blk, 0, stream>>>(ao, x1, ln2_g, ln2_b, out, nullptr);
}

// Round 8
// 144.153 us; speedup vs baseline: 1.0562x; 1.0034x over previous
//
#include <hip/hip_runtime.h>
#include <hip/hip_bf16.h>
#include <math.h>

#define B_   16
#define C_   512
#define D_   256
#define K_   16
#define RD_  128
#define H_   8
#define HD_  32
#define FFN_ 1024
#define M_   (B_ * C_)   // 8192 rows

typedef __attribute__((ext_vector_type(8))) short bf16x8;
typedef __attribute__((ext_vector_type(4))) float f32x4;

typedef __attribute__((address_space(1))) const int ga_int;
typedef __attribute__((address_space(3))) int ls_int;

static __device__ __forceinline__ short f2bf(float v) {
    __hip_bfloat16 h = __float2bfloat16(v);
    return *(short*)&h;
}

// ---------------------------------------------------------------------------
// All fp32->bf16 conversions in ONE kernel.
// ---------------------------------------------------------------------------
#define N8_X    (M_ * D_ / 8)
#define N8_INW  (768 * D_ / 8)
#define N8_OUTW (D_ * D_ / 8)
#define N8_W1   (FFN_ * D_ / 8)
#define N8_W2   (D_ * FFN_ / 8)
#define N8_TOT  (N8_X + N8_INW + N8_OUTW + N8_W1 + N8_W2)

__global__ __launch_bounds__(256) void convert_all_kernel(
    const float* __restrict__ x, const float* __restrict__ inw,
    const float* __restrict__ outw, const float* __restrict__ w1,
    const float* __restrict__ w2,
    short* __restrict__ xbf, short* __restrict__ inwbf,
    short* __restrict__ outwbf, short* __restrict__ w1bf,
    short* __restrict__ w2bf)
{
    int i = blockIdx.x * 256 + threadIdx.x;
    const float* s; short* d; int off;
    if      (i < N8_X)                          { s = x;    d = xbf;    off = i; }
    else if (i < N8_X + N8_INW)                 { s = inw;  d = inwbf;  off = i - N8_X; }
    else if (i < N8_X + N8_INW + N8_OUTW)       { s = outw; d = outwbf; off = i - N8_X - N8_INW; }
    else if (i < N8_X + N8_INW + N8_OUTW + N8_W1){ s = w1;  d = w1bf;   off = i - N8_X - N8_INW - N8_OUTW; }
    else if (i < N8_TOT)                        { s = w2;   d = w2bf;   off = i - N8_X - N8_INW - N8_OUTW - N8_W1; }
    else return;
    const float4* sp = (const float4*)s + (size_t)off * 2;
    float4 v0 = sp[0], v1 = sp[1];
    short r[8];
    r[0]=f2bf(v0.x); r[1]=f2bf(v0.y); r[2]=f2bf(v0.z); r[3]=f2bf(v0.w);
    r[4]=f2bf(v1.x); r[5]=f2bf(v1.y); r[6]=f2bf(v1.z); r[7]=f2bf(v1.w);
    *(bf16x8*)(d + (size_t)off * 8) = *(bf16x8*)r;
}

// ---------------------------------------------------------------------------
// bf16 MFMA GEMM: C[M,N] = A[M,Kd] @ W[N,Kd]^T + bias (+exact GELU).
// Template BM/BN; 256 threads = 4 waves in 2x2, each (BM/2)x(BN/2).
// Double-buffered global_load_lds staging.
// ---------------------------------------------------------------------------
template<int BM, int BN, int OUT_BF16, int ACT>
__global__ __launch_bounds__(256) void gemm_mfma(
    const short* __restrict__ A, const short* __restrict__ W,
    const float* __restrict__ bias, void* __restrict__ Cout,
    int M, int N, int Kd)
{
    __shared__ short As[2][BM * 32];
    __shared__ short Bs[2][BN * 32];
    const int tid  = threadIdx.x;
    const int wave = tid >> 6;
    const int lane = tid & 63;
    const int bm = blockIdx.y * BM;
    const int bn = blockIdx.x * BN;
    constexpr int MI = BM / 32;
    constexpr int NJ = BN / 32;
    const int wr = (wave >> 1) * (BM / 2);
    const int wc = (wave & 1) * (BN / 2);

    const int fr = lane & 15;          // fragment row within 16
    const int fk = (lane >> 4) * 8;    // fragment k offset (shorts)

    const int r0 = tid >> 2, ch = (tid & 3) * 8;   // staging row / chunk

    f32x4 acc[MI][NJ];
    #pragma unroll
    for (int i = 0; i < MI; ++i)
        #pragma unroll
        for (int j = 0; j < NJ; ++j)
            acc[i][j] = (f32x4){0.f, 0.f, 0.f, 0.f};

    auto stage = [&](int buf, int k0) {
        #pragma unroll
        for (int i = 0; i < BM / 64; ++i)
            __builtin_amdgcn_global_load_lds(
                (ga_int*)&A[(size_t)(bm + r0 + i * 64) * Kd + k0 + ch],
                (ls_int*)&As[buf][(tid + i * 256) * 8], 16, 0, 0);
        #pragma unroll
        for (int j = 0; j < BN / 64; ++j)
            __builtin_amdgcn_global_load_lds(
                (ga_int*)&W[(size_t)(bn + r0 + j * 64) * Kd + k0 + ch],
                (ls_int*)&Bs[buf][(tid + j * 256) * 8], 16, 0, 0);
    };

    stage(0, 0);
    int cur = 0;

    for (int k0 = 0; k0 < Kd; k0 += 32) {
        __syncthreads();
        if (k0 + 32 < Kd) stage(cur ^ 1, k0 + 32);

        bf16x8 af[MI], bfr[NJ];
        #pragma unroll
        for (int i = 0; i < MI; ++i) af[i]  = *(bf16x8*)&As[cur][(wr + i * 16 + fr) * 32 + fk];
        #pragma unroll
        for (int j = 0; j < NJ; ++j) bfr[j] = *(bf16x8*)&Bs[cur][(wc + j * 16 + fr) * 32 + fk];
        #pragma unroll
        for (int i = 0; i < MI; ++i)
            #pragma unroll
            for (int j = 0; j < NJ; ++j)
                acc[i][j] = __builtin_amdgcn_mfma_f32_16x16x32_bf16(af[i], bfr[j], acc[i][j], 0, 0, 0);
        cur ^= 1;
    }

    const int rowbase = (lane >> 4) * 4;
    #pragma unroll
    for (int i = 0; i < MI; ++i) {
        #pragma unroll
        for (int j = 0; j < NJ; ++j) {
            const int n = bn + wc + j * 16 + fr;
            const float bn_v = bias ? bias[n] : 0.f;
            #pragma unroll
            for (int r = 0; r < 4; ++r) {
                const int m = bm + wr + i * 16 + rowbase + r;
                float v = acc[i][j][r] + bn_v;
                if (ACT) v = 0.5f * v * (1.0f + erff(v * 0.70710678118654752f));
                if (OUT_BF16) ((short*)Cout)[(size_t)m * N + n] = f2bf(v);
                else          ((float*)Cout)[(size_t)m * N + n] = v;
            }
        }
    }
}

// ---------------------------------------------------------------------------
// Fused xq/xk fp32 GEMM (exact, feeds top-k). blockIdx.z: 0 -> xq, 1 -> xk.
// 64x64 tile, 4x4 micro, float4-vectorized staging; accumulation order
// unchanged (sequential kk, sequential K-tiles) -> bit-identical outputs.
// ---------------------------------------------------------------------------
__global__ __launch_bounds__(256) void xqk_gemm(
    const float* __restrict__ x, const float* __restrict__ wq,
    const float* __restrict__ wk, float* __restrict__ xqo,
    float* __restrict__ xko)
{
    __shared__ float As[16 * 68];
    __shared__ float Ws[16 * 68];
    const float* Wm = blockIdx.z ? wk : wq;
    float* Cm       = blockIdx.z ? xko : xqo;

    const int tid = threadIdx.x;
    const int tx = tid & 15;
    const int ty = tid >> 4;
    const int bm = blockIdx.y * 64;
    const int bn = blockIdx.x * 64;

    const int sr = tid >> 2, sq = (tid & 3) * 4;   // staging: 256 float4

    float acc[4][4] = {};

    for (int k0 = 0; k0 < D_; k0 += 16) {
        {
            float4 va = *(const float4*)&x[(size_t)(bm + sr) * D_ + k0 + sq];
            As[(sq + 0) * 68 + sr] = va.x;
            As[(sq + 1) * 68 + sr] = va.y;
            As[(sq + 2) * 68 + sr] = va.z;
            As[(sq + 3) * 68 + sr] = va.w;
            float4 vw = *(const float4*)&Wm[(size_t)(bn + sr) * D_ + k0 + sq];
            Ws[(sq + 0) * 68 + sr] = vw.x;
            Ws[(sq + 1) * 68 + sr] = vw.y;
            Ws[(sq + 2) * 68 + sr] = vw.z;
            Ws[(sq + 3) * 68 + sr] = vw.w;
        }
        __syncthreads();
        #pragma unroll
        for (int kk = 0; kk < 16; ++kk) {
            float4 a = *(const float4*)&As[kk * 68 + ty * 4];
            float4 w = *(const float4*)&Ws[kk * 68 + tx * 4];
            float av[4] = {a.x, a.y, a.z, a.w};
            float wv[4] = {w.x, w.y, w.z, w.w};
            #pragma unroll
            for (int i = 0; i < 4; ++i)
                #pragma unroll
                for (int j = 0; j < 4; ++j)
                    acc[i][j] += av[i] * wv[j];
        }
        __syncthreads();
    }

    #pragma unroll
    for (int i = 0; i < 4; ++i)
        #pragma unroll
        for (int j = 0; j < 4; ++j)
            Cm[(size_t)(bm + ty * 4 + i) * RD_ + bn + tx * 4 + j] = acc[i][j];
}

// ---------------------------------------------------------------------------
// Batched logits GEMM (fp32, exact): logits[b,q,c] = xq[b,q,:] . xk[b,c,:]
// 128x64 tile, 8x4 micro (LDS-traffic: 3 b128 reads per 32 FMA vs 2 per 16),
// grid 512 = 2 blocks/CU. Accumulation order unchanged -> bit-identical.
// ---------------------------------------------------------------------------
__global__ __launch_bounds__(256) void logits_gemm(
    const float* __restrict__ xq, const float* __restrict__ xk,
    float* __restrict__ out)
{
    __shared__ float As[16 * 132];   // [kk][row 0..127], pad 132
    __shared__ float Ws[16 * 68];    // [kk][col 0..63],  pad 68
    const int tid = threadIdx.x;
    const int tx = tid & 15;         // col group (x4)
    const int ty = tid >> 4;         // row group (x8)
    const int bm = blockIdx.y * 128;
    const int bn = blockIdx.x * 64;
    const int b  = blockIdx.z;

    const float* A = xq + (size_t)b * C_ * RD_;
    const float* W = xk + (size_t)b * C_ * RD_;
    float* Cmat    = out + (size_t)b * C_ * C_;

    const int sr = tid >> 2, sq = (tid & 3) * 4;   // B staging: 256 f4

    float acc[8][4] = {};

    for (int k0 = 0; k0 < RD_; k0 += 16) {
        #pragma unroll
        for (int e = 0; e < 2; ++e) {              // A staging: 512 f4
            int t = tid + e * 256;
            int r = t >> 2, q = (t & 3) * 4;
            float4 va = *(const float4*)&A[(size_t)(bm + r) * RD_ + k0 + q];
            As[(q + 0) * 132 + r] = va.x;
            As[(q + 1) * 132 + r] = va.y;
            As[(q + 2) * 132 + r] = va.z;
            As[(q + 3) * 132 + r] = va.w;
        }
        {
            float4 vw = *(const float4*)&W[(size_t)(bn + sr) * RD_ + k0 + sq];
            Ws[(sq + 0) * 68 + sr] = vw.x;
            Ws[(sq + 1) * 68 + sr] = vw.y;
            Ws[(sq + 2) * 68 + sr] = vw.z;
            Ws[(sq + 3) * 68 + sr] = vw.w;
        }
        __syncthreads();
        #pragma unroll
        for (int kk = 0; kk < 16; ++kk) {
            float4 a0 = *(const float4*)&As[kk * 132 + ty * 8];
            float4 a1 = *(const float4*)&As[kk * 132 + ty * 8 + 4];
            float4 w  = *(const float4*)&Ws[kk * 68 + tx * 4];
            float av[8] = {a0.x, a0.y, a0.z, a0.w, a1.x, a1.y, a1.z, a1.w};
            float wv[4] = {w.x, w.y, w.z, w.w};
            #pragma unroll
            for (int i = 0; i < 8; ++i)
                #pragma unroll
                for (int j = 0; j < 4; ++j)
                    acc[i][j] += av[i] * wv[j];
        }
        __syncthreads();
    }

    #pragma unroll
    for (int i = 0; i < 8; ++i)
        #pragma unroll
        for (int j = 0; j < 4; ++j)
            Cmat[(size_t)(bm + ty * 8 + i) * C_ + bn + tx * 4 + j] = acc[i][j];
}

// ---------------------------------------------------------------------------
// FUSED top-16 + attention, ONE WAVE per (b,q) row, zero barriers.
// ---------------------------------------------------------------------------
__global__ __launch_bounds__(256) void topk_attn_kernel(
    const float* __restrict__ logits, const float* __restrict__ qkv,
    short* __restrict__ ctxbf)
{
    const int wave = threadIdx.x >> 6;
    const int lane = threadIdx.x & 63;
    const int row  = blockIdx.x * 4 + wave;        // global (b*C + q)
    const int bbase = row & ~(C_ - 1);             // batch base row

    // ---- top-16 ----
    const float* lrow = logits + (size_t)row * C_;
    unsigned long long key[8];
    #pragma unroll
    for (int j = 0; j < 8; ++j) {
        int pos = lane * 8 + j;
        unsigned u = __float_as_uint(lrow[pos]);
        u = (u & 0x80000000u) ? ~u : (u | 0x80000000u);
        key[j] = (((unsigned long long)u) << 9) | (unsigned)(511 - pos);
    }

    int ii[K_];
    #pragma unroll
    for (int sel = 0; sel < K_; ++sel) {
        unsigned long long best = key[0];
        #pragma unroll
        for (int j = 1; j < 8; ++j) best = key[j] > best ? key[j] : best;
        #pragma unroll
        for (int s = 1; s < 64; s <<= 1) {
            unsigned long long o = __shfl_xor(best, s, 64);
            best = o > best ? o : best;
        }
        int pos = 511 - (int)(best & 511ull);      // wave-uniform
        ii[sel] = pos;
        if ((pos >> 3) == lane) key[pos & 7] = 0ull;
    }

    // ---- attention over the 16 selected slots ----
    const float* qrow = qkv + (size_t)row * 768;
    float4 qv = *(const float4*)(qrow + lane * 4);

    float s[K_];
    #pragma unroll
    for (int k = 0; k < K_; ++k) {
        const float* kr = qkv + (size_t)(bbase + ii[k]) * 768 + 256;
        float4 kv = *(const float4*)(kr + lane * 4);
        float p = qv.x * kv.x + qv.y * kv.y + qv.z * kv.z + qv.w * kv.w;
        p += __shfl_xor(p, 1, 64);
        p += __shfl_xor(p, 2, 64);
        p += __shfl_xor(p, 4, 64);
        s[k] = p * 0.17677669529663687f;
    }

    float m = s[0];
    #pragma unroll
    for (int k = 1; k < K_; ++k) m = fmaxf(m, s[k]);
    float ssum = 0.f;
    #pragma unroll
    for (int k = 0; k < K_; ++k) { s[k] = __expf(s[k] - m); ssum += s[k]; }
    const float inv = 1.f / ssum;

    float4 acc = {0.f, 0.f, 0.f, 0.f};
    #pragma unroll
    for (int k = 0; k < K_; ++k) {
        const float* vr = qkv + (size_t)(bbase + ii[k]) * 768 + 512;
        float4 vv = *(const float4*)(vr + lane * 4);
        float w = s[k] * inv;
        acc.x += w * vv.x; acc.y += w * vv.y; acc.z += w * vv.z; acc.w += w * vv.w;
    }

    unsigned lo = (unsigned)(unsigned short)f2bf(acc.x) | ((unsigned)(unsigned short)f2bf(acc.y) << 16);
    unsigned hi = (unsigned)(unsigned short)f2bf(acc.z) | ((unsigned)(unsigned short)f2bf(acc.w) << 16);
    uint2 pk = {lo, hi};
    *(uint2*)(ctxbf + (size_t)row * D_ + lane * 4) = pk;
}

// ---------------------------------------------------------------------------
// out = LN(a + res), ONE WAVE per row (shuffle reductions, no barriers).
// ---------------------------------------------------------------------------
template<int WBF>
__global__ __launch_bounds__(256) void add_ln_wave_kernel(
    const float* __restrict__ a, const float* __restrict__ res,
    const float* __restrict__ g, const float* __restrict__ beta,
    float* __restrict__ out, short* __restrict__ outbf)
{
    const int wave = threadIdx.x >> 6;
    const int lane = threadIdx.x & 63;
    const int row  = blockIdx.x * 4 + wave;

    float4 va = *(const float4*)(a   + (size_t)row * D_ + lane * 4);
    float4 vr = *(const float4*)(res + (size_t)row * D_ + lane * 4);
    float4 v = {va.x + vr.x, va.y + vr.y, va.z + vr.z, va.w + vr.w};

    float t = v.x + v.y + v.z + v.w;
    #pragma unroll
    for (int s = 1; s < 64; s <<= 1) t += __shfl_xor(t, s, 64);
    const float mean = t * (1.0f / D_);

    float4 dv = {v.x - mean, v.y - mean, v.z - mean, v.w - mean};
    float sq = dv.x * dv.x + dv.y * dv.y + dv.z * dv.z + dv.w * dv.w;
    #pragma unroll
    for (int s = 1; s < 64; s <<= 1) sq += __shfl_xor(sq, s, 64);
    const float rstd = rsqrtf(sq * (1.0f / D_) + 1e-5f);

    float4 gv = *(const float4*)(g    + lane * 4);
    float4 bv = *(const float4*)(beta + lane * 4);
    float4 o = {dv.x * rstd * gv.x + bv.x, dv.y * rstd * gv.y + bv.y,
                dv.z * rstd * gv.z + bv.z, dv.w * rstd * gv.w + bv.w};
    *(float4*)(out + (size_t)row * D_ + lane * 4) = o;
    if (WBF) {
        unsigned lo = (unsigned)(unsigned short)f2bf(o.x) | ((unsigned)(unsigned short)f2bf(o.y) << 16);
        unsigned hi = (unsigned)(unsigned short)f2bf(o.z) | ((unsigned)(unsigned short)f2bf(o.w) << 16);
        uint2 pk = {lo, hi};
        *(uint2*)(outbf + (size_t)row * D_ + lane * 4) = pk;
    }
}

// ---------------------------------------------------------------------------
extern "C" void kernel_launch(void* const* d_in, const int* in_sizes, int n_in,
                              void* d_out, int out_size, void* d_ws, size_t ws_size,
                              hipStream_t stream)
{
    const float* x      = (const float*)d_in[0];
    const float* wq_rec = (const float*)d_in[1];
    const float* wk_rec = (const float*)d_in[2];
    const float* in_w   = (const float*)d_in[3];
    const float* in_b   = (const float*)d_in[4];
    const float* out_w  = (const float*)d_in[5];
    const float* out_b  = (const float*)d_in[6];
    const float* ln1_g  = (const float*)d_in[7];
    const float* ln1_b  = (const float*)d_in[8];
    const float* w1     = (const float*)d_in[9];
    const float* b1     = (const float*)d_in[10];
    const float* w2     = (const float*)d_in[11];
    const float* b2     = (const float*)d_in[12];
    const float* ln2_g  = (const float*)d_in[13];
    const float* ln2_b  = (const float*)d_in[14];
    float* out = (float*)d_out;

    // ---- workspace layout (floats) ----
    float* ws = (float*)d_ws;
    float* qkv   = ws;                              // M*768 f
    float* xq    = qkv + (size_t)M_ * 768;          // M*128 f
    float* xk    = xq  + (size_t)M_ * RD_;          // M*128 f
    float* x1    = xk  + (size_t)M_ * RD_;          // M*256 f
    float* ao    = x1 + (size_t)M_ * D_;            // M*256 f
    float* U     = ao + (size_t)M_ * D_;            // union region
    float* logits = U;                                  // M*512 f      (topk phase)
    short* ctxbf  = (short*)U;                          // M*256 bf16   (attn->outproj)
    short* x1bf   = (short*)U + (size_t)M_ * D_;        // M*256 bf16   (ln1->mlp1)
    short* hbf    = (short*)U + (size_t)2 * M_ * D_;    // M*1024 bf16  (mlp1->mlp2)
    float* afterU = U + (size_t)3 * M_ * D_;
    short* xbf    = (short*)afterU;                     // M*256 bf16
    short* inwbf  = xbf   + (size_t)M_ * D_;
    short* outwbf = inwbf + (size_t)768 * D_;
    short* w1bf   = outwbf + (size_t)D_ * D_;
    short* w2bf   = w1bf  + (size_t)FFN_ * D_;

    dim3 blk(256);

    // 0) all bf16 conversions, one launch
    convert_all_kernel<<<dim3((N8_TOT + 255) / 256), blk, 0, stream>>>(
        x, in_w, out_w, w1, w2, xbf, inwbf, outwbf, w1bf, w2bf);

    // 1) qkv = x @ in_proj_w^T + b  (MFMA, 64x128 -> 768 blocks)
    gemm_mfma<64, 128, 0, 0><<<dim3(768 / 128, M_ / 64), blk, 0, stream>>>(xbf, inwbf, in_b, qkv, M_, 768, D_);
    // 2) xq/xk recurrence projections (fp32 exact), 64x64 tile, 512 blocks
    xqk_gemm<<<dim3(RD_ / 64, M_ / 64, 2), blk, 0, stream>>>(x, wq_rec, wk_rec, xq, xk);
    // 3) logits (fp32 exact), 128x64 tile, 8x4 micro, 512 blocks
    logits_gemm<<<dim3(C_ / 64, C_ / 128, B_), blk, 0, stream>>>(xq, xk, logits);
    // 4) fused top-16 + gathered attention -> ctx (bf16)
    topk_attn_kernel<<<dim3(M_ / 4), blk, 0, stream>>>(logits, qkv, ctxbf);
    // 5) out projection (MFMA, 64x64 -> 512 blocks)
    gemm_mfma<64, 64, 0, 0><<<dim3(D_ / 64, M_ / 64), blk, 0, stream>>>(ctxbf, outwbf, out_b, ao, M_, D_, D_);
    // 6) x1 = LN(attn_out + x), + bf16 copy
    add_ln_wave_kernel<1><<<dim3(M_ / 4), blk, 0, stream>>>(ao, x, ln1_g, ln1_b, x1, x1bf);
    // 7) h = gelu(x1 @ w1^T + b1) (MFMA, 128x128 -> 512 blocks, bf16 out)
    gemm_mfma<128, 128, 1, 1><<<dim3(FFN_ / 128, M_ / 128), blk, 0, stream>>>(x1bf, w1bf, b1, hbf, M_, FFN_, D_);
    // 8) y = h @ w2^T + b2 (MFMA, 64x64 -> 512 blocks)
    gemm_mfma<64, 64, 0, 0><<<dim3(D_ / 64, M_ / 64), blk, 0, stream>>>(hbf, w2bf, b2, ao, M_, D_, FFN_);
    // 9) out = LN(y + x1)
    add_ln_wave_kernel<0><<<dim3(M_ / 4), blk, 0, stream>>>(ao, x1, ln2_g, ln2_b, out, nullptr);
}

// Round 9
// 123.860 us; speedup vs baseline: 1.2292x; 1.1638x over previous
//
#include <hip/hip_runtime.h>
#include <hip/hip_bf16.h>
#include <math.h>

#define B_   16
#define C_   512
#define D_   256
#define K_   16
#define RD_  128
#define H_   8
#define HD_  32
#define FFN_ 1024
#define M_   (B_ * C_)   // 8192 rows

typedef __attribute__((ext_vector_type(8))) short bf16x8;
typedef __attribute__((ext_vector_type(4))) float f32x4;

typedef __attribute__((address_space(1))) const int ga_int;
typedef __attribute__((address_space(3))) int ls_int;

static __device__ __forceinline__ short f2bf(float v) {
    __hip_bfloat16 h = __float2bfloat16(v);
    return *(short*)&h;
}
static __device__ __forceinline__ float bf2f(short s) {
    __hip_bfloat16 h = *(__hip_bfloat16*)&s;
    return __bfloat162float(h);
}

// ---------------------------------------------------------------------------
// All fp32->bf16 conversions in ONE kernel. x also emits a LO split;
// wq_rec/wk_rec emit HI+LO splits (for split-bf16 MFMA logits path).
// ---------------------------------------------------------------------------
#define N8_X    (M_ * D_ / 8)
#define N8_INW  (768 * D_ / 8)
#define N8_OUTW (D_ * D_ / 8)
#define N8_W1   (FFN_ * D_ / 8)
#define N8_W2   (D_ * FFN_ / 8)
#define N8_WQ   (RD_ * D_ / 8)
#define N8_ALL  (N8_X + N8_INW + N8_OUTW + N8_W1 + N8_W2 + 2 * N8_WQ)

__global__ __launch_bounds__(256) void convert_all_kernel(
    const float* __restrict__ x, const float* __restrict__ inw,
    const float* __restrict__ outw, const float* __restrict__ w1,
    const float* __restrict__ w2, const float* __restrict__ wq,
    const float* __restrict__ wk,
    short* __restrict__ xbf, short* __restrict__ xlo,
    short* __restrict__ inwbf, short* __restrict__ outwbf,
    short* __restrict__ w1bf, short* __restrict__ w2bf,
    short* __restrict__ wqh, short* __restrict__ wql,
    short* __restrict__ wkh, short* __restrict__ wkl)
{
    int i = blockIdx.x * 256 + threadIdx.x;
    if (i >= N8_ALL) return;

    const float* s; short* dh; short* dl = nullptr; int off;
    if      (i < N8_X)                    { s = x;    dh = xbf;    dl = xlo; off = i; }
    else if (i < N8_X + N8_INW)           { s = inw;  dh = inwbf;  off = i - N8_X; }
    else if (i < N8_X + N8_INW + N8_OUTW) { s = outw; dh = outwbf; off = i - N8_X - N8_INW; }
    else if (i < N8_X + N8_INW + N8_OUTW + N8_W1)
                                          { s = w1;   dh = w1bf;   off = i - N8_X - N8_INW - N8_OUTW; }
    else if (i < N8_X + N8_INW + N8_OUTW + N8_W1 + N8_W2)
                                          { s = w2;   dh = w2bf;   off = i - N8_X - N8_INW - N8_OUTW - N8_W1; }
    else if (i < N8_X + N8_INW + N8_OUTW + N8_W1 + N8_W2 + N8_WQ)
                                          { s = wq;   dh = wqh; dl = wql; off = i - N8_X - N8_INW - N8_OUTW - N8_W1 - N8_W2; }
    else                                  { s = wk;   dh = wkh; dl = wkl; off = i - N8_X - N8_INW - N8_OUTW - N8_W1 - N8_W2 - N8_WQ; }

    const float4* sp = (const float4*)s + (size_t)off * 2;
    float4 v0 = sp[0], v1 = sp[1];
    float f[8] = {v0.x, v0.y, v0.z, v0.w, v1.x, v1.y, v1.z, v1.w};
    short rh[8], rl[8];
    #pragma unroll
    for (int j = 0; j < 8; ++j) {
        rh[j] = f2bf(f[j]);
        rl[j] = f2bf(f[j] - bf2f(rh[j]));
    }
    *(bf16x8*)(dh + (size_t)off * 8) = *(bf16x8*)rh;
    if (dl) *(bf16x8*)(dl + (size_t)off * 8) = *(bf16x8*)rl;
}

// ---------------------------------------------------------------------------
// bf16 MFMA GEMM: C[M,N] = A[M,Kd] @ W[N,Kd]^T + bias (+exact GELU).
// Template BM/BN; 256 threads = 4 waves in 2x2, each (BM/2)x(BN/2).
// Double-buffered global_load_lds staging.
// ---------------------------------------------------------------------------
template<int BM, int BN, int OUT_BF16, int ACT>
__global__ __launch_bounds__(256) void gemm_mfma(
    const short* __restrict__ A, const short* __restrict__ W,
    const float* __restrict__ bias, void* __restrict__ Cout,
    int M, int N, int Kd)
{
    __shared__ short As[2][BM * 32];
    __shared__ short Bs[2][BN * 32];
    const int tid  = threadIdx.x;
    const int wave = tid >> 6;
    const int lane = tid & 63;
    const int bm = blockIdx.y * BM;
    const int bn = blockIdx.x * BN;
    constexpr int MI = BM / 32;
    constexpr int NJ = BN / 32;
    const int wr = (wave >> 1) * (BM / 2);
    const int wc = (wave & 1) * (BN / 2);

    const int fr = lane & 15;
    const int fk = (lane >> 4) * 8;

    const int r0 = tid >> 2, ch = (tid & 3) * 8;

    f32x4 acc[MI][NJ];
    #pragma unroll
    for (int i = 0; i < MI; ++i)
        #pragma unroll
        for (int j = 0; j < NJ; ++j)
            acc[i][j] = (f32x4){0.f, 0.f, 0.f, 0.f};

    auto stage = [&](int buf, int k0) {
        #pragma unroll
        for (int i = 0; i < BM / 64; ++i)
            __builtin_amdgcn_global_load_lds(
                (ga_int*)&A[(size_t)(bm + r0 + i * 64) * Kd + k0 + ch],
                (ls_int*)&As[buf][(tid + i * 256) * 8], 16, 0, 0);
        #pragma unroll
        for (int j = 0; j < BN / 64; ++j)
            __builtin_amdgcn_global_load_lds(
                (ga_int*)&W[(size_t)(bn + r0 + j * 64) * Kd + k0 + ch],
                (ls_int*)&Bs[buf][(tid + j * 256) * 8], 16, 0, 0);
    };

    stage(0, 0);
    int cur = 0;

    for (int k0 = 0; k0 < Kd; k0 += 32) {
        __syncthreads();
        if (k0 + 32 < Kd) stage(cur ^ 1, k0 + 32);

        bf16x8 af[MI], bfr[NJ];
        #pragma unroll
        for (int i = 0; i < MI; ++i) af[i]  = *(bf16x8*)&As[cur][(wr + i * 16 + fr) * 32 + fk];
        #pragma unroll
        for (int j = 0; j < NJ; ++j) bfr[j] = *(bf16x8*)&Bs[cur][(wc + j * 16 + fr) * 32 + fk];
        #pragma unroll
        for (int i = 0; i < MI; ++i)
            #pragma unroll
            for (int j = 0; j < NJ; ++j)
                acc[i][j] = __builtin_amdgcn_mfma_f32_16x16x32_bf16(af[i], bfr[j], acc[i][j], 0, 0, 0);
        cur ^= 1;
    }

    const int rowbase = (lane >> 4) * 4;
    #pragma unroll
    for (int i = 0; i < MI; ++i) {
        #pragma unroll
        for (int j = 0; j < NJ; ++j) {
            const int n = bn + wc + j * 16 + fr;
            const float bn_v = bias ? bias[n] : 0.f;
            #pragma unroll
            for (int r = 0; r < 4; ++r) {
                const int m = bm + wr + i * 16 + rowbase + r;
                float v = acc[i][j][r] + bn_v;
                if (ACT) v = 0.5f * v * (1.0f + erff(v * 0.70710678118654752f));
                if (OUT_BF16) ((short*)Cout)[(size_t)m * N + n] = f2bf(v);
                else          ((float*)Cout)[(size_t)m * N + n] = v;
            }
        }
    }
}

// ---------------------------------------------------------------------------
// Split-bf16 MFMA xq/xk projection: xq = xh@Wh^T + xh@Wl^T + xl@Wh^T
// (lo*lo dropped, rel err ~1e-5). 64x64 tile, K=256, blockIdx.z: 0=q, 1=k.
// Epilogue emits hi/lo bf16 split of the result directly (feeds logits_mfma).
// ---------------------------------------------------------------------------
__global__ __launch_bounds__(256) void xqk_mfma(
    const short* __restrict__ xh, const short* __restrict__ xl,
    const short* __restrict__ wqh, const short* __restrict__ wql,
    const short* __restrict__ wkh, const short* __restrict__ wkl,
    short* __restrict__ qh, short* __restrict__ ql,
    short* __restrict__ kh, short* __restrict__ kl)
{
    __shared__ short Ah[64 * 32], Al[64 * 32], Bh[64 * 32], Bl[64 * 32];
    const short* Wh = blockIdx.z ? wkh : wqh;
    const short* Wl = blockIdx.z ? wkl : wql;
    short* Oh       = blockIdx.z ? kh : qh;
    short* Ol       = blockIdx.z ? kl : ql;

    const int tid  = threadIdx.x;
    const int wave = tid >> 6;
    const int lane = tid & 63;
    const int bm = blockIdx.y * 64;
    const int bn = blockIdx.x * 64;
    const int wr = (wave >> 1) * 32;
    const int wc = (wave & 1) * 32;
    const int fr = lane & 15;
    const int fk = (lane >> 4) * 8;
    const int r0 = tid >> 2, ch = (tid & 3) * 8;

    f32x4 acc[2][2];
    #pragma unroll
    for (int i = 0; i < 2; ++i)
        #pragma unroll
        for (int j = 0; j < 2; ++j)
            acc[i][j] = (f32x4){0.f, 0.f, 0.f, 0.f};

    for (int k0 = 0; k0 < D_; k0 += 32) {
        __builtin_amdgcn_global_load_lds((ga_int*)&xh[(size_t)(bm + r0) * D_ + k0 + ch], (ls_int*)&Ah[tid * 8], 16, 0, 0);
        __builtin_amdgcn_global_load_lds((ga_int*)&xl[(size_t)(bm + r0) * D_ + k0 + ch], (ls_int*)&Al[tid * 8], 16, 0, 0);
        __builtin_amdgcn_global_load_lds((ga_int*)&Wh[(size_t)(bn + r0) * D_ + k0 + ch], (ls_int*)&Bh[tid * 8], 16, 0, 0);
        __builtin_amdgcn_global_load_lds((ga_int*)&Wl[(size_t)(bn + r0) * D_ + k0 + ch], (ls_int*)&Bl[tid * 8], 16, 0, 0);
        __syncthreads();

        bf16x8 ah[2], al[2], bh[2], bl[2];
        #pragma unroll
        for (int i = 0; i < 2; ++i) {
            ah[i] = *(bf16x8*)&Ah[(wr + i * 16 + fr) * 32 + fk];
            al[i] = *(bf16x8*)&Al[(wr + i * 16 + fr) * 32 + fk];
        }
        #pragma unroll
        for (int j = 0; j < 2; ++j) {
            bh[j] = *(bf16x8*)&Bh[(wc + j * 16 + fr) * 32 + fk];
            bl[j] = *(bf16x8*)&Bl[(wc + j * 16 + fr) * 32 + fk];
        }
        #pragma unroll
        for (int i = 0; i < 2; ++i)
            #pragma unroll
            for (int j = 0; j < 2; ++j) {
                acc[i][j] = __builtin_amdgcn_mfma_f32_16x16x32_bf16(ah[i], bh[j], acc[i][j], 0, 0, 0);
                acc[i][j] = __builtin_amdgcn_mfma_f32_16x16x32_bf16(ah[i], bl[j], acc[i][j], 0, 0, 0);
                acc[i][j] = __builtin_amdgcn_mfma_f32_16x16x32_bf16(al[i], bh[j], acc[i][j], 0, 0, 0);
            }
        __syncthreads();
    }

    const int rowbase = (lane >> 4) * 4;
    #pragma unroll
    for (int i = 0; i < 2; ++i)
        #pragma unroll
        for (int j = 0; j < 2; ++j) {
            const int n = bn + wc + j * 16 + fr;
            #pragma unroll
            for (int r = 0; r < 4; ++r) {
                const int m = bm + wr + i * 16 + rowbase + r;
                float v = acc[i][j][r];
                short h = f2bf(v);
                Oh[(size_t)m * RD_ + n] = h;
                Ol[(size_t)m * RD_ + n] = f2bf(v - bf2f(h));
            }
        }
}

// ---------------------------------------------------------------------------
// Split-bf16 MFMA logits: logits[b,q,c] = qh.kh + qh.kl + ql.kh (fp32 out).
// Per batch 512x512, K=128. 64x64 tile -> grid (8,8,16) = 1024 blocks.
// ---------------------------------------------------------------------------
__global__ __launch_bounds__(256) void logits_mfma(
    const short* __restrict__ qh, const short* __restrict__ ql,
    const short* __restrict__ kh, const short* __restrict__ kl,
    float* __restrict__ out)
{
    __shared__ short Ah[64 * 32], Al[64 * 32], Bh[64 * 32], Bl[64 * 32];
    const int tid  = threadIdx.x;
    const int wave = tid >> 6;
    const int lane = tid & 63;
    const int base = blockIdx.z * C_;          // batch row base
    const int bm = blockIdx.y * 64;
    const int bn = blockIdx.x * 64;
    const int wr = (wave >> 1) * 32;
    const int wc = (wave & 1) * 32;
    const int fr = lane & 15;
    const int fk = (lane >> 4) * 8;
    const int r0 = tid >> 2, ch = (tid & 3) * 8;

    f32x4 acc[2][2];
    #pragma unroll
    for (int i = 0; i < 2; ++i)
        #pragma unroll
        for (int j = 0; j < 2; ++j)
            acc[i][j] = (f32x4){0.f, 0.f, 0.f, 0.f};

    for (int k0 = 0; k0 < RD_; k0 += 32) {
        __builtin_amdgcn_global_load_lds((ga_int*)&qh[(size_t)(base + bm + r0) * RD_ + k0 + ch], (ls_int*)&Ah[tid * 8], 16, 0, 0);
        __builtin_amdgcn_global_load_lds((ga_int*)&ql[(size_t)(base + bm + r0) * RD_ + k0 + ch], (ls_int*)&Al[tid * 8], 16, 0, 0);
        __builtin_amdgcn_global_load_lds((ga_int*)&kh[(size_t)(base + bn + r0) * RD_ + k0 + ch], (ls_int*)&Bh[tid * 8], 16, 0, 0);
        __builtin_amdgcn_global_load_lds((ga_int*)&kl[(size_t)(base + bn + r0) * RD_ + k0 + ch], (ls_int*)&Bl[tid * 8], 16, 0, 0);
        __syncthreads();

        bf16x8 ah[2], al[2], bh[2], bl[2];
        #pragma unroll
        for (int i = 0; i < 2; ++i) {
            ah[i] = *(bf16x8*)&Ah[(wr + i * 16 + fr) * 32 + fk];
            al[i] = *(bf16x8*)&Al[(wr + i * 16 + fr) * 32 + fk];
        }
        #pragma unroll
        for (int j = 0; j < 2; ++j) {
            bh[j] = *(bf16x8*)&Bh[(wc + j * 16 + fr) * 32 + fk];
            bl[j] = *(bf16x8*)&Bl[(wc + j * 16 + fr) * 32 + fk];
        }
        #pragma unroll
        for (int i = 0; i < 2; ++i)
            #pragma unroll
            for (int j = 0; j < 2; ++j) {
                acc[i][j] = __builtin_amdgcn_mfma_f32_16x16x32_bf16(ah[i], bh[j], acc[i][j], 0, 0, 0);
                acc[i][j] = __builtin_amdgcn_mfma_f32_16x16x32_bf16(ah[i], bl[j], acc[i][j], 0, 0, 0);
                acc[i][j] = __builtin_amdgcn_mfma_f32_16x16x32_bf16(al[i], bh[j], acc[i][j], 0, 0, 0);
            }
        __syncthreads();
    }

    const int rowbase = (lane >> 4) * 4;
    #pragma unroll
    for (int i = 0; i < 2; ++i)
        #pragma unroll
        for (int j = 0; j < 2; ++j) {
            const int n = bn + wc + j * 16 + fr;
            #pragma unroll
            for (int r = 0; r < 4; ++r) {
                const int m = base + bm + wr + i * 16 + rowbase + r;
                out[(size_t)m * C_ + n] = acc[i][j][r];
            }
        }
}

// ---------------------------------------------------------------------------
// FUSED top-16 + attention, ONE WAVE per (b,q) row, zero barriers.
// ---------------------------------------------------------------------------
__global__ __launch_bounds__(256) void topk_attn_kernel(
    const float* __restrict__ logits, const float* __restrict__ qkv,
    short* __restrict__ ctxbf)
{
    const int wave = threadIdx.x >> 6;
    const int lane = threadIdx.x & 63;
    const int row  = blockIdx.x * 4 + wave;        // global (b*C + q)
    const int bbase = row & ~(C_ - 1);             // batch base row

    // ---- top-16 ----
    const float* lrow = logits + (size_t)row * C_;
    unsigned long long key[8];
    #pragma unroll
    for (int j = 0; j < 8; ++j) {
        int pos = lane * 8 + j;
        unsigned u = __float_as_uint(lrow[pos]);
        u = (u & 0x80000000u) ? ~u : (u | 0x80000000u);
        key[j] = (((unsigned long long)u) << 9) | (unsigned)(511 - pos);
    }

    int ii[K_];
    #pragma unroll
    for (int sel = 0; sel < K_; ++sel) {
        unsigned long long best = key[0];
        #pragma unroll
        for (int j = 1; j < 8; ++j) best = key[j] > best ? key[j] : best;
        #pragma unroll
        for (int s = 1; s < 64; s <<= 1) {
            unsigned long long o = __shfl_xor(best, s, 64);
            best = o > best ? o : best;
        }
        int pos = 511 - (int)(best & 511ull);      // wave-uniform
        ii[sel] = pos;
        if ((pos >> 3) == lane) key[pos & 7] = 0ull;
    }

    // ---- attention over the 16 selected slots ----
    const float* qrow = qkv + (size_t)row * 768;
    float4 qv = *(const float4*)(qrow + lane * 4);

    float s[K_];
    #pragma unroll
    for (int k = 0; k < K_; ++k) {
        const float* kr = qkv + (size_t)(bbase + ii[k]) * 768 + 256;
        float4 kv = *(const float4*)(kr + lane * 4);
        float p = qv.x * kv.x + qv.y * kv.y + qv.z * kv.z + qv.w * kv.w;
        p += __shfl_xor(p, 1, 64);
        p += __shfl_xor(p, 2, 64);
        p += __shfl_xor(p, 4, 64);
        s[k] = p * 0.17677669529663687f;
    }

    float m = s[0];
    #pragma unroll
    for (int k = 1; k < K_; ++k) m = fmaxf(m, s[k]);
    float ssum = 0.f;
    #pragma unroll
    for (int k = 0; k < K_; ++k) { s[k] = __expf(s[k] - m); ssum += s[k]; }
    const float inv = 1.f / ssum;

    float4 acc = {0.f, 0.f, 0.f, 0.f};
    #pragma unroll
    for (int k = 0; k < K_; ++k) {
        const float* vr = qkv + (size_t)(bbase + ii[k]) * 768 + 512;
        float4 vv = *(const float4*)(vr + lane * 4);
        float w = s[k] * inv;
        acc.x += w * vv.x; acc.y += w * vv.y; acc.z += w * vv.z; acc.w += w * vv.w;
    }

    unsigned lo = (unsigned)(unsigned short)f2bf(acc.x) | ((unsigned)(unsigned short)f2bf(acc.y) << 16);
    unsigned hi = (unsigned)(unsigned short)f2bf(acc.z) | ((unsigned)(unsigned short)f2bf(acc.w) << 16);
    uint2 pk = {lo, hi};
    *(uint2*)(ctxbf + (size_t)row * D_ + lane * 4) = pk;
}

// ---------------------------------------------------------------------------
// out = LN(a + res), ONE WAVE per row (shuffle reductions, no barriers).
// ---------------------------------------------------------------------------
template<int WBF>
__global__ __launch_bounds__(256) void add_ln_wave_kernel(
    const float* __restrict__ a, const float* __restrict__ res,
    const float* __restrict__ g, const float* __restrict__ beta,
    float* __restrict__ out, short* __restrict__ outbf)
{
    const int wave = threadIdx.x >> 6;
    const int lane = threadIdx.x & 63;
    const int row  = blockIdx.x * 4 + wave;

    float4 va = *(const float4*)(a   + (size_t)row * D_ + lane * 4);
    float4 vr = *(const float4*)(res + (size_t)row * D_ + lane * 4);
    float4 v = {va.x + vr.x, va.y + vr.y, va.z + vr.z, va.w + vr.w};

    float t = v.x + v.y + v.z + v.w;
    #pragma unroll
    for (int s = 1; s < 64; s <<= 1) t += __shfl_xor(t, s, 64);
    const float mean = t * (1.0f / D_);

    float4 dv = {v.x - mean, v.y - mean, v.z - mean, v.w - mean};
    float sq = dv.x * dv.x + dv.y * dv.y + dv.z * dv.z + dv.w * dv.w;
    #pragma unroll
    for (int s = 1; s < 64; s <<= 1) sq += __shfl_xor(sq, s, 64);
    const float rstd = rsqrtf(sq * (1.0f / D_) + 1e-5f);

    float4 gv = *(const float4*)(g    + lane * 4);
    float4 bv = *(const float4*)(beta + lane * 4);
    float4 o = {dv.x * rstd * gv.x + bv.x, dv.y * rstd * gv.y + bv.y,
                dv.z * rstd * gv.z + bv.z, dv.w * rstd * gv.w + bv.w};
    *(float4*)(out + (size_t)row * D_ + lane * 4) = o;
    if (WBF) {
        unsigned lo = (unsigned)(unsigned short)f2bf(o.x) | ((unsigned)(unsigned short)f2bf(o.y) << 16);
        unsigned hi = (unsigned)(unsigned short)f2bf(o.z) | ((unsigned)(unsigned short)f2bf(o.w) << 16);
        uint2 pk = {lo, hi};
        *(uint2*)(outbf + (size_t)row * D_ + lane * 4) = pk;
    }
}

// ---------------------------------------------------------------------------
extern "C" void kernel_launch(void* const* d_in, const int* in_sizes, int n_in,
                              void* d_out, int out_size, void* d_ws, size_t ws_size,
                              hipStream_t stream)
{
    const float* x      = (const float*)d_in[0];
    const float* wq_rec = (const float*)d_in[1];
    const float* wk_rec = (const float*)d_in[2];
    const float* in_w   = (const float*)d_in[3];
    const float* in_b   = (const float*)d_in[4];
    const float* out_w  = (const float*)d_in[5];
    const float* out_b  = (const float*)d_in[6];
    const float* ln1_g  = (const float*)d_in[7];
    const float* ln1_b  = (const float*)d_in[8];
    const float* w1     = (const float*)d_in[9];
    const float* b1     = (const float*)d_in[10];
    const float* w2     = (const float*)d_in[11];
    const float* b2     = (const float*)d_in[12];
    const float* ln2_g  = (const float*)d_in[13];
    const float* ln2_b  = (const float*)d_in[14];
    float* out = (float*)d_out;

    // ---- workspace layout ----
    float* ws = (float*)d_ws;
    float* qkv   = ws;                              // M*768 f
    short* qh    = (short*)(qkv + (size_t)M_ * 768);// M*128 sh
    short* ql    = qh + (size_t)M_ * RD_;           // M*128 sh
    short* kh    = ql + (size_t)M_ * RD_;           // M*128 sh
    short* kl    = kh + (size_t)M_ * RD_;           // M*128 sh (tot = M*256 f)
    float* x1    = (float*)(kl + (size_t)M_ * RD_); // M*256 f
    float* ao    = x1 + (size_t)M_ * D_;            // M*256 f
    float* U     = ao + (size_t)M_ * D_;            // union region
    float* logits = U;                                  // M*512 f      (topk phase)
    short* ctxbf  = (short*)U;                          // M*256 bf16   (attn->outproj)
    short* x1bf   = (short*)U + (size_t)M_ * D_;        // M*256 bf16   (ln1->mlp1)
    short* hbf    = (short*)U + (size_t)2 * M_ * D_;    // M*1024 bf16  (mlp1->mlp2)
    float* afterU = U + (size_t)3 * M_ * D_;
    short* xbf    = (short*)afterU;                     // M*256 bf16
    short* xlo    = xbf   + (size_t)M_ * D_;            // M*256 bf16
    short* inwbf  = xlo   + (size_t)M_ * D_;
    short* outwbf = inwbf + (size_t)768 * D_;
    short* w1bf   = outwbf + (size_t)D_ * D_;
    short* w2bf   = w1bf  + (size_t)FFN_ * D_;
    short* wqh    = w2bf  + (size_t)D_ * FFN_;
    short* wql    = wqh + (size_t)RD_ * D_;
    short* wkh    = wql + (size_t)RD_ * D_;
    short* wkl    = wkh + (size_t)RD_ * D_;

    dim3 blk(256);

    // 0) all bf16 conversions (+ hi/lo splits), one launch
    convert_all_kernel<<<dim3((N8_ALL + 255) / 256), blk, 0, stream>>>(
        x, in_w, out_w, w1, w2, wq_rec, wk_rec,
        xbf, xlo, inwbf, outwbf, w1bf, w2bf, wqh, wql, wkh, wkl);

    // 1) qkv = x @ in_proj_w^T + b  (MFMA, 64x128 -> 768 blocks)
    gemm_mfma<64, 128, 0, 0><<<dim3(768 / 128, M_ / 64), blk, 0, stream>>>(xbf, inwbf, in_b, qkv, M_, 768, D_);
    // 2) xq/xk projections, split-bf16 MFMA -> qh/ql/kh/kl (512 blocks)
    xqk_mfma<<<dim3(RD_ / 64, M_ / 64, 2), blk, 0, stream>>>(
        xbf, xlo, wqh, wql, wkh, wkl, qh, ql, kh, kl);
    // 3) logits, split-bf16 MFMA (1024 blocks)
    logits_mfma<<<dim3(C_ / 64, C_ / 64, B_), blk, 0, stream>>>(qh, ql, kh, kl, logits);
    // 4) fused top-16 + gathered attention -> ctx (bf16)
    topk_attn_kernel<<<dim3(M_ / 4), blk, 0, stream>>>(logits, qkv, ctxbf);
    // 5) out projection (MFMA, 64x64 -> 512 blocks)
    gemm_mfma<64, 64, 0, 0><<<dim3(D_ / 64, M_ / 64), blk, 0, stream>>>(ctxbf, outwbf, out_b, ao, M_, D_, D_);
    // 6) x1 = LN(attn_out + x), + bf16 copy
    add_ln_wave_kernel<1><<<dim3(M_ / 4), blk, 0, stream>>>(ao, x, ln1_g, ln1_b, x1, x1bf);
    // 7) h = gelu(x1 @ w1^T + b1) (MFMA, 128x128 -> 512 blocks, bf16 out)
    gemm_mfma<128, 128, 1, 1><<<dim3(FFN_ / 128, M_ / 128), blk, 0, stream>>>(x1bf, w1bf, b1, hbf, M_, FFN_, D_);
    // 8) y = h @ w2^T + b2 (MFMA, 64x64 -> 512 blocks)
    gemm_mfma<64, 64, 0, 0><<<dim3(D_ / 64, M_ / 64), blk, 0, stream>>>(hbf, w2bf, b2, ao, M_, D_, FFN_);
    // 9) out = LN(y + x1)
    add_ln_wave_kernel<0><<<dim3(M_ / 4), blk, 0, stream>>>(ao, x1, ln2_g, ln2_b, out, nullptr);
}

// Round 10
// 123.122 us; speedup vs baseline: 1.2366x; 1.0060x over previous
//
#include <hip/hip_runtime.h>
#include <hip/hip_bf16.h>
#include <math.h>

#define B_   16
#define C_   512
#define D_   256
#define K_   16
#define RD_  128
#define H_   8
#define HD_  32
#define FFN_ 1024
#define M_   (B_ * C_)   // 8192 rows

typedef __attribute__((ext_vector_type(8))) short bf16x8;
typedef __attribute__((ext_vector_type(4))) float f32x4;

typedef __attribute__((address_space(1))) const int ga_int;
typedef __attribute__((address_space(3))) int ls_int;

static __device__ __forceinline__ short f2bf(float v) {
    __hip_bfloat16 h = __float2bfloat16(v);
    return *(short*)&h;
}
static __device__ __forceinline__ float bf2f(short s) {
    __hip_bfloat16 h = *(__hip_bfloat16*)&s;
    return __bfloat162float(h);
}
static __device__ __forceinline__ float4 ld4bf(const short* p) {
    uint2 u = *(const uint2*)p;
    float4 r;
    r.x = __uint_as_float((u.x & 0xffffu) << 16);
    r.y = __uint_as_float(u.x & 0xffff0000u);
    r.z = __uint_as_float((u.y & 0xffffu) << 16);
    r.w = __uint_as_float(u.y & 0xffff0000u);
    return r;
}

// ---------------------------------------------------------------------------
// All fp32->bf16 conversions in ONE kernel. x emits HI+LO; wq/wk emit HI+LO.
// ---------------------------------------------------------------------------
#define N8_X    (M_ * D_ / 8)
#define N8_INW  (768 * D_ / 8)
#define N8_OUTW (D_ * D_ / 8)
#define N8_W1   (FFN_ * D_ / 8)
#define N8_W2   (D_ * FFN_ / 8)
#define N8_WQ   (RD_ * D_ / 8)
#define N8_ALL  (N8_X + N8_INW + N8_OUTW + N8_W1 + N8_W2 + 2 * N8_WQ)

__global__ __launch_bounds__(256) void convert_all_kernel(
    const float* __restrict__ x, const float* __restrict__ inw,
    const float* __restrict__ outw, const float* __restrict__ w1,
    const float* __restrict__ w2, const float* __restrict__ wq,
    const float* __restrict__ wk,
    short* __restrict__ xbf, short* __restrict__ xlo,
    short* __restrict__ inwbf, short* __restrict__ outwbf,
    short* __restrict__ w1bf, short* __restrict__ w2bf,
    short* __restrict__ wqh, short* __restrict__ wql,
    short* __restrict__ wkh, short* __restrict__ wkl)
{
    int i = blockIdx.x * 256 + threadIdx.x;
    if (i >= N8_ALL) return;

    const float* s; short* dh; short* dl = nullptr; int off;
    if      (i < N8_X)                    { s = x;    dh = xbf;    dl = xlo; off = i; }
    else if (i < N8_X + N8_INW)           { s = inw;  dh = inwbf;  off = i - N8_X; }
    else if (i < N8_X + N8_INW + N8_OUTW) { s = outw; dh = outwbf; off = i - N8_X - N8_INW; }
    else if (i < N8_X + N8_INW + N8_OUTW + N8_W1)
                                          { s = w1;   dh = w1bf;   off = i - N8_X - N8_INW - N8_OUTW; }
    else if (i < N8_X + N8_INW + N8_OUTW + N8_W1 + N8_W2)
                                          { s = w2;   dh = w2bf;   off = i - N8_X - N8_INW - N8_OUTW - N8_W1; }
    else if (i < N8_X + N8_INW + N8_OUTW + N8_W1 + N8_W2 + N8_WQ)
                                          { s = wq;   dh = wqh; dl = wql; off = i - N8_X - N8_INW - N8_OUTW - N8_W1 - N8_W2; }
    else                                  { s = wk;   dh = wkh; dl = wkl; off = i - N8_X - N8_INW - N8_OUTW - N8_W1 - N8_W2 - N8_WQ; }

    const float4* sp = (const float4*)s + (size_t)off * 2;
    float4 v0 = sp[0], v1 = sp[1];
    float f[8] = {v0.x, v0.y, v0.z, v0.w, v1.x, v1.y, v1.z, v1.w};
    short rh[8], rl[8];
    #pragma unroll
    for (int j = 0; j < 8; ++j) {
        rh[j] = f2bf(f[j]);
        rl[j] = f2bf(f[j] - bf2f(rh[j]));
    }
    *(bf16x8*)(dh + (size_t)off * 8) = *(bf16x8*)rh;
    if (dl) *(bf16x8*)(dl + (size_t)off * 8) = *(bf16x8*)rl;
}

// ---------------------------------------------------------------------------
// bf16 MFMA GEMM: C[M,N] = A[M,Kd] @ W[N,Kd]^T + bias (+exact GELU).
// Template BM/BN; 256 threads = 4 waves in 2x2. Double-buffered
// global_load_lds staging.
// ---------------------------------------------------------------------------
template<int BM, int BN, int OUT_BF16, int ACT>
__global__ __launch_bounds__(256) void gemm_mfma(
    const short* __restrict__ A, const short* __restrict__ W,
    const float* __restrict__ bias, void* __restrict__ Cout,
    int M, int N, int Kd)
{
    __shared__ short As[2][BM * 32];
    __shared__ short Bs[2][BN * 32];
    const int tid  = threadIdx.x;
    const int wave = tid >> 6;
    const int lane = tid & 63;
    const int bm = blockIdx.y * BM;
    const int bn = blockIdx.x * BN;
    constexpr int MI = BM / 32;
    constexpr int NJ = BN / 32;
    const int wr = (wave >> 1) * (BM / 2);
    const int wc = (wave & 1) * (BN / 2);

    const int fr = lane & 15;
    const int fk = (lane >> 4) * 8;
    const int r0 = tid >> 2, ch = (tid & 3) * 8;

    f32x4 acc[MI][NJ];
    #pragma unroll
    for (int i = 0; i < MI; ++i)
        #pragma unroll
        for (int j = 0; j < NJ; ++j)
            acc[i][j] = (f32x4){0.f, 0.f, 0.f, 0.f};

    auto stage = [&](int buf, int k0) {
        #pragma unroll
        for (int i = 0; i < BM / 64; ++i)
            __builtin_amdgcn_global_load_lds(
                (ga_int*)&A[(size_t)(bm + r0 + i * 64) * Kd + k0 + ch],
                (ls_int*)&As[buf][(tid + i * 256) * 8], 16, 0, 0);
        #pragma unroll
        for (int j = 0; j < BN / 64; ++j)
            __builtin_amdgcn_global_load_lds(
                (ga_int*)&W[(size_t)(bn + r0 + j * 64) * Kd + k0 + ch],
                (ls_int*)&Bs[buf][(tid + j * 256) * 8], 16, 0, 0);
    };

    stage(0, 0);
    int cur = 0;

    for (int k0 = 0; k0 < Kd; k0 += 32) {
        __syncthreads();
        if (k0 + 32 < Kd) stage(cur ^ 1, k0 + 32);

        bf16x8 af[MI], bfr[NJ];
        #pragma unroll
        for (int i = 0; i < MI; ++i) af[i]  = *(bf16x8*)&As[cur][(wr + i * 16 + fr) * 32 + fk];
        #pragma unroll
        for (int j = 0; j < NJ; ++j) bfr[j] = *(bf16x8*)&Bs[cur][(wc + j * 16 + fr) * 32 + fk];
        #pragma unroll
        for (int i = 0; i < MI; ++i)
            #pragma unroll
            for (int j = 0; j < NJ; ++j)
                acc[i][j] = __builtin_amdgcn_mfma_f32_16x16x32_bf16(af[i], bfr[j], acc[i][j], 0, 0, 0);
        cur ^= 1;
    }

    const int rowbase = (lane >> 4) * 4;
    #pragma unroll
    for (int i = 0; i < MI; ++i) {
        #pragma unroll
        for (int j = 0; j < NJ; ++j) {
            const int n = bn + wc + j * 16 + fr;
            const float bn_v = bias ? bias[n] : 0.f;
            #pragma unroll
            for (int r = 0; r < 4; ++r) {
                const int m = bm + wr + i * 16 + rowbase + r;
                float v = acc[i][j][r] + bn_v;
                if (ACT) v = 0.5f * v * (1.0f + erff(v * 0.70710678118654752f));
                if (OUT_BF16) ((short*)Cout)[(size_t)m * N + n] = f2bf(v);
                else          ((float*)Cout)[(size_t)m * N + n] = v;
            }
        }
    }
}

// ---------------------------------------------------------------------------
// FUSED GEMM + bias + residual-add + LayerNorm (fp32 out, optional bf16 out).
// C row = LN(A@W^T + bias + res). BM=32, BN=256 (full row in one block),
// 4 waves tile N (wave w -> cols w*64..w*64+63), each 32x64 (MI=2, NJ=4).
// Cross-wave LN reduction via shfl (16-lane groups) + 1KB LDS partials.
// ---------------------------------------------------------------------------
template<int KD, int WBF>
__global__ __launch_bounds__(256) void gemm_ln_mfma(
    const short* __restrict__ A, const short* __restrict__ W,
    const float* __restrict__ bias, const float* __restrict__ res,
    const float* __restrict__ g, const float* __restrict__ beta,
    float* __restrict__ out, short* __restrict__ outbf)
{
    __shared__ short As[2][32 * 32];
    __shared__ short Bs[2][256 * 32];
    __shared__ float part[4][32][2];

    const int tid  = threadIdx.x;
    const int wave = tid >> 6;
    const int lane = tid & 63;
    const int bm = blockIdx.x * 32;
    const int wc = wave * 64;
    const int fr = lane & 15;
    const int fk = (lane >> 4) * 8;
    const int r0 = tid >> 2, ch = (tid & 3) * 8;

    f32x4 acc[2][4];
    #pragma unroll
    for (int i = 0; i < 2; ++i)
        #pragma unroll
        for (int j = 0; j < 4; ++j)
            acc[i][j] = (f32x4){0.f, 0.f, 0.f, 0.f};

    auto stage = [&](int buf, int k0) {
        if (tid < 128)
            __builtin_amdgcn_global_load_lds(
                (ga_int*)&A[(size_t)(bm + r0) * KD + k0 + ch],
                (ls_int*)&As[buf][tid * 8], 16, 0, 0);
        #pragma unroll
        for (int j = 0; j < 4; ++j)
            __builtin_amdgcn_global_load_lds(
                (ga_int*)&W[(size_t)(r0 + j * 64) * KD + k0 + ch],
                (ls_int*)&Bs[buf][(tid + j * 256) * 8], 16, 0, 0);
    };

    stage(0, 0);
    int cur = 0;

    for (int k0 = 0; k0 < KD; k0 += 32) {
        __syncthreads();
        if (k0 + 32 < KD) stage(cur ^ 1, k0 + 32);

        bf16x8 af[2], bfr[4];
        #pragma unroll
        for (int i = 0; i < 2; ++i) af[i]  = *(bf16x8*)&As[cur][(i * 16 + fr) * 32 + fk];
        #pragma unroll
        for (int j = 0; j < 4; ++j) bfr[j] = *(bf16x8*)&Bs[cur][(wc + j * 16 + fr) * 32 + fk];
        #pragma unroll
        for (int i = 0; i < 2; ++i)
            #pragma unroll
            for (int j = 0; j < 4; ++j)
                acc[i][j] = __builtin_amdgcn_mfma_f32_16x16x32_bf16(af[i], bfr[j], acc[i][j], 0, 0, 0);
        cur ^= 1;
    }

    // ---- epilogue: v = acc + bias + res; row-wise LN over 256 cols ----
    const int rowbase = (lane >> 4) * 4;
    float vv[2][4][4];
    float sum[2][4], sq[2][4];
    #pragma unroll
    for (int i = 0; i < 2; ++i)
        #pragma unroll
        for (int r = 0; r < 4; ++r) { sum[i][r] = 0.f; sq[i][r] = 0.f; }

    #pragma unroll
    for (int i = 0; i < 2; ++i)
        #pragma unroll
        for (int j = 0; j < 4; ++j) {
            const int n = wc + j * 16 + fr;
            const float bv = bias[n];
            #pragma unroll
            for (int r = 0; r < 4; ++r) {
                const int m = bm + i * 16 + rowbase + r;
                float v = acc[i][j][r] + bv + res[(size_t)m * D_ + n];
                vv[i][j][r] = v;
                sum[i][r] += v;
                sq[i][r]  += v * v;
            }
        }

    // reduce over the 16 fr-lanes (xor of bits 0..3 stays in group)
    #pragma unroll
    for (int i = 0; i < 2; ++i)
        #pragma unroll
        for (int r = 0; r < 4; ++r)
            #pragma unroll
            for (int s = 1; s < 16; s <<= 1) {
                sum[i][r] += __shfl_xor(sum[i][r], s, 64);
                sq[i][r]  += __shfl_xor(sq[i][r],  s, 64);
            }

    if (fr == 0) {
        #pragma unroll
        for (int i = 0; i < 2; ++i)
            #pragma unroll
            for (int r = 0; r < 4; ++r) {
                int ml = i * 16 + rowbase + r;
                part[wave][ml][0] = sum[i][r];
                part[wave][ml][1] = sq[i][r];
            }
    }
    __syncthreads();

    #pragma unroll
    for (int i = 0; i < 2; ++i)
        #pragma unroll
        for (int r = 0; r < 4; ++r) {
            const int ml = i * 16 + rowbase + r;
            const float S = part[0][ml][0] + part[1][ml][0] + part[2][ml][0] + part[3][ml][0];
            const float Q = part[0][ml][1] + part[1][ml][1] + part[2][ml][1] + part[3][ml][1];
            const float mean = S * (1.0f / D_);
            const float var  = Q * (1.0f / D_) - mean * mean;
            const float rstd = rsqrtf(var + 1e-5f);
            const int m = bm + ml;
            #pragma unroll
            for (int j = 0; j < 4; ++j) {
                const int n = wc + j * 16 + fr;
                float o = (vv[i][j][r] - mean) * rstd * g[n] + beta[n];
                out[(size_t)m * D_ + n] = o;
                if (WBF) outbf[(size_t)m * D_ + n] = f2bf(o);
            }
        }
}

// ---------------------------------------------------------------------------
// Split-bf16 MFMA xq/xk projection (exact-enough, feeds top-k).
// ---------------------------------------------------------------------------
__global__ __launch_bounds__(256) void xqk_mfma(
    const short* __restrict__ xh, const short* __restrict__ xl,
    const short* __restrict__ wqh, const short* __restrict__ wql,
    const short* __restrict__ wkh, const short* __restrict__ wkl,
    short* __restrict__ qh, short* __restrict__ ql,
    short* __restrict__ kh, short* __restrict__ kl)
{
    __shared__ short Ah[64 * 32], Al[64 * 32], Bh[64 * 32], Bl[64 * 32];
    const short* Wh = blockIdx.z ? wkh : wqh;
    const short* Wl = blockIdx.z ? wkl : wql;
    short* Oh       = blockIdx.z ? kh : qh;
    short* Ol       = blockIdx.z ? kl : ql;

    const int tid  = threadIdx.x;
    const int wave = tid >> 6;
    const int lane = tid & 63;
    const int bm = blockIdx.y * 64;
    const int bn = blockIdx.x * 64;
    const int wr = (wave >> 1) * 32;
    const int wc = (wave & 1) * 32;
    const int fr = lane & 15;
    const int fk = (lane >> 4) * 8;
    const int r0 = tid >> 2, ch = (tid & 3) * 8;

    f32x4 acc[2][2];
    #pragma unroll
    for (int i = 0; i < 2; ++i)
        #pragma unroll
        for (int j = 0; j < 2; ++j)
            acc[i][j] = (f32x4){0.f, 0.f, 0.f, 0.f};

    for (int k0 = 0; k0 < D_; k0 += 32) {
        __builtin_amdgcn_global_load_lds((ga_int*)&xh[(size_t)(bm + r0) * D_ + k0 + ch], (ls_int*)&Ah[tid * 8], 16, 0, 0);
        __builtin_amdgcn_global_load_lds((ga_int*)&xl[(size_t)(bm + r0) * D_ + k0 + ch], (ls_int*)&Al[tid * 8], 16, 0, 0);
        __builtin_amdgcn_global_load_lds((ga_int*)&Wh[(size_t)(bn + r0) * D_ + k0 + ch], (ls_int*)&Bh[tid * 8], 16, 0, 0);
        __builtin_amdgcn_global_load_lds((ga_int*)&Wl[(size_t)(bn + r0) * D_ + k0 + ch], (ls_int*)&Bl[tid * 8], 16, 0, 0);
        __syncthreads();

        bf16x8 ah[2], al[2], bh[2], bl[2];
        #pragma unroll
        for (int i = 0; i < 2; ++i) {
            ah[i] = *(bf16x8*)&Ah[(wr + i * 16 + fr) * 32 + fk];
            al[i] = *(bf16x8*)&Al[(wr + i * 16 + fr) * 32 + fk];
        }
        #pragma unroll
        for (int j = 0; j < 2; ++j) {
            bh[j] = *(bf16x8*)&Bh[(wc + j * 16 + fr) * 32 + fk];
            bl[j] = *(bf16x8*)&Bl[(wc + j * 16 + fr) * 32 + fk];
        }
        #pragma unroll
        for (int i = 0; i < 2; ++i)
            #pragma unroll
            for (int j = 0; j < 2; ++j) {
                acc[i][j] = __builtin_amdgcn_mfma_f32_16x16x32_bf16(ah[i], bh[j], acc[i][j], 0, 0, 0);
                acc[i][j] = __builtin_amdgcn_mfma_f32_16x16x32_bf16(ah[i], bl[j], acc[i][j], 0, 0, 0);
                acc[i][j] = __builtin_amdgcn_mfma_f32_16x16x32_bf16(al[i], bh[j], acc[i][j], 0, 0, 0);
            }
        __syncthreads();
    }

    const int rowbase = (lane >> 4) * 4;
    #pragma unroll
    for (int i = 0; i < 2; ++i)
        #pragma unroll
        for (int j = 0; j < 2; ++j) {
            const int n = bn + wc + j * 16 + fr;
            #pragma unroll
            for (int r = 0; r < 4; ++r) {
                const int m = bm + wr + i * 16 + rowbase + r;
                float v = acc[i][j][r];
                short h = f2bf(v);
                Oh[(size_t)m * RD_ + n] = h;
                Ol[(size_t)m * RD_ + n] = f2bf(v - bf2f(h));
            }
        }
}

// ---------------------------------------------------------------------------
// Split-bf16 MFMA logits: logits[b,q,c] = qh.kh + qh.kl + ql.kh (fp32 out).
// ---------------------------------------------------------------------------
__global__ __launch_bounds__(256) void logits_mfma(
    const short* __restrict__ qh, const short* __restrict__ ql,
    const short* __restrict__ kh, const short* __restrict__ kl,
    float* __restrict__ out)
{
    __shared__ short Ah[64 * 32], Al[64 * 32], Bh[64 * 32], Bl[64 * 32];
    const int tid  = threadIdx.x;
    const int wave = tid >> 6;
    const int lane = tid & 63;
    const int base = blockIdx.z * C_;
    const int bm = blockIdx.y * 64;
    const int bn = blockIdx.x * 64;
    const int wr = (wave >> 1) * 32;
    const int wc = (wave & 1) * 32;
    const int fr = lane & 15;
    const int fk = (lane >> 4) * 8;
    const int r0 = tid >> 2, ch = (tid & 3) * 8;

    f32x4 acc[2][2];
    #pragma unroll
    for (int i = 0; i < 2; ++i)
        #pragma unroll
        for (int j = 0; j < 2; ++j)
            acc[i][j] = (f32x4){0.f, 0.f, 0.f, 0.f};

    for (int k0 = 0; k0 < RD_; k0 += 32) {
        __builtin_amdgcn_global_load_lds((ga_int*)&qh[(size_t)(base + bm + r0) * RD_ + k0 + ch], (ls_int*)&Ah[tid * 8], 16, 0, 0);
        __builtin_amdgcn_global_load_lds((ga_int*)&ql[(size_t)(base + bm + r0) * RD_ + k0 + ch], (ls_int*)&Al[tid * 8], 16, 0, 0);
        __builtin_amdgcn_global_load_lds((ga_int*)&kh[(size_t)(base + bn + r0) * RD_ + k0 + ch], (ls_int*)&Bh[tid * 8], 16, 0, 0);
        __builtin_amdgcn_global_load_lds((ga_int*)&kl[(size_t)(base + bn + r0) * RD_ + k0 + ch], (ls_int*)&Bl[tid * 8], 16, 0, 0);
        __syncthreads();

        bf16x8 ah[2], al[2], bh[2], bl[2];
        #pragma unroll
        for (int i = 0; i < 2; ++i) {
            ah[i] = *(bf16x8*)&Ah[(wr + i * 16 + fr) * 32 + fk];
            al[i] = *(bf16x8*)&Al[(wr + i * 16 + fr) * 32 + fk];
        }
        #pragma unroll
        for (int j = 0; j < 2; ++j) {
            bh[j] = *(bf16x8*)&Bh[(wc + j * 16 + fr) * 32 + fk];
            bl[j] = *(bf16x8*)&Bl[(wc + j * 16 + fr) * 32 + fk];
        }
        #pragma unroll
        for (int i = 0; i < 2; ++i)
            #pragma unroll
            for (int j = 0; j < 2; ++j) {
                acc[i][j] = __builtin_amdgcn_mfma_f32_16x16x32_bf16(ah[i], bh[j], acc[i][j], 0, 0, 0);
                acc[i][j] = __builtin_amdgcn_mfma_f32_16x16x32_bf16(ah[i], bl[j], acc[i][j], 0, 0, 0);
                acc[i][j] = __builtin_amdgcn_mfma_f32_16x16x32_bf16(al[i], bh[j], acc[i][j], 0, 0, 0);
            }
        __syncthreads();
    }

    const int rowbase = (lane >> 4) * 4;
    #pragma unroll
    for (int i = 0; i < 2; ++i)
        #pragma unroll
        for (int j = 0; j < 2; ++j) {
            const int n = bn + wc + j * 16 + fr;
            #pragma unroll
            for (int r = 0; r < 4; ++r) {
                const int m = base + bm + wr + i * 16 + rowbase + r;
                out[(size_t)m * C_ + n] = acc[i][j][r];
            }
        }
}

// ---------------------------------------------------------------------------
// FUSED top-16 + attention, ONE WAVE per (b,q) row. qkv is bf16.
// ---------------------------------------------------------------------------
__global__ __launch_bounds__(256) void topk_attn_kernel(
    const float* __restrict__ logits, const short* __restrict__ qkv,
    short* __restrict__ ctxbf)
{
    const int wave = threadIdx.x >> 6;
    const int lane = threadIdx.x & 63;
    const int row  = blockIdx.x * 4 + wave;
    const int bbase = row & ~(C_ - 1);

    // ---- top-16 ----
    const float* lrow = logits + (size_t)row * C_;
    unsigned long long key[8];
    #pragma unroll
    for (int j = 0; j < 8; ++j) {
        int pos = lane * 8 + j;
        unsigned u = __float_as_uint(lrow[pos]);
        u = (u & 0x80000000u) ? ~u : (u | 0x80000000u);
        key[j] = (((unsigned long long)u) << 9) | (unsigned)(511 - pos);
    }

    int ii[K_];
    #pragma unroll
    for (int sel = 0; sel < K_; ++sel) {
        unsigned long long best = key[0];
        #pragma unroll
        for (int j = 1; j < 8; ++j) best = key[j] > best ? key[j] : best;
        #pragma unroll
        for (int s = 1; s < 64; s <<= 1) {
            unsigned long long o = __shfl_xor(best, s, 64);
            best = o > best ? o : best;
        }
        int pos = 511 - (int)(best & 511ull);
        ii[sel] = pos;
        if ((pos >> 3) == lane) key[pos & 7] = 0ull;
    }

    // ---- attention over the 16 selected slots (bf16 loads, fp32 math) ----
    const short* qrow = qkv + (size_t)row * 768;
    float4 qv = ld4bf(qrow + lane * 4);

    float s[K_];
    #pragma unroll
    for (int k = 0; k < K_; ++k) {
        float4 kv = ld4bf(qkv + (size_t)(bbase + ii[k]) * 768 + 256 + lane * 4);
        float p = qv.x * kv.x + qv.y * kv.y + qv.z * kv.z + qv.w * kv.w;
        p += __shfl_xor(p, 1, 64);
        p += __shfl_xor(p, 2, 64);
        p += __shfl_xor(p, 4, 64);
        s[k] = p * 0.17677669529663687f;
    }

    float m = s[0];
    #pragma unroll
    for (int k = 1; k < K_; ++k) m = fmaxf(m, s[k]);
    float ssum = 0.f;
    #pragma unroll
    for (int k = 0; k < K_; ++k) { s[k] = __expf(s[k] - m); ssum += s[k]; }
    const float inv = 1.f / ssum;

    float4 acc = {0.f, 0.f, 0.f, 0.f};
    #pragma unroll
    for (int k = 0; k < K_; ++k) {
        float4 vvv = ld4bf(qkv + (size_t)(bbase + ii[k]) * 768 + 512 + lane * 4);
        float w = s[k] * inv;
        acc.x += w * vvv.x; acc.y += w * vvv.y; acc.z += w * vvv.z; acc.w += w * vvv.w;
    }

    unsigned lo = (unsigned)(unsigned short)f2bf(acc.x) | ((unsigned)(unsigned short)f2bf(acc.y) << 16);
    unsigned hi = (unsigned)(unsigned short)f2bf(acc.z) | ((unsigned)(unsigned short)f2bf(acc.w) << 16);
    uint2 pk = {lo, hi};
    *(uint2*)(ctxbf + (size_t)row * D_ + lane * 4) = pk;
}

// ---------------------------------------------------------------------------
extern "C" void kernel_launch(void* const* d_in, const int* in_sizes, int n_in,
                              void* d_out, int out_size, void* d_ws, size_t ws_size,
                              hipStream_t stream)
{
    const float* x      = (const float*)d_in[0];
    const float* wq_rec = (const float*)d_in[1];
    const float* wk_rec = (const float*)d_in[2];
    const float* in_w   = (const float*)d_in[3];
    const float* in_b   = (const float*)d_in[4];
    const float* out_w  = (const float*)d_in[5];
    const float* out_b  = (const float*)d_in[6];
    const float* ln1_g  = (const float*)d_in[7];
    const float* ln1_b  = (const float*)d_in[8];
    const float* w1     = (const float*)d_in[9];
    const float* b1     = (const float*)d_in[10];
    const float* w2     = (const float*)d_in[11];
    const float* b2     = (const float*)d_in[12];
    const float* ln2_g  = (const float*)d_in[13];
    const float* ln2_b  = (const float*)d_in[14];
    float* out = (float*)d_out;

    // ---- workspace layout ----
    short* qkvbf = (short*)d_ws;                    // M*768 sh (bf16 q|k|v)
    short* qh    = qkvbf + (size_t)M_ * 768;        // M*128 sh
    short* ql    = qh + (size_t)M_ * RD_;
    short* kh    = ql + (size_t)M_ * RD_;
    short* kl    = kh + (size_t)M_ * RD_;
    float* x1    = (float*)(kl + (size_t)M_ * RD_); // M*256 f  (16B-aligned)
    float* U     = x1 + (size_t)M_ * D_;
    float* logits = U;                                  // M*512 f
    short* ctxbf  = (short*)(U + (size_t)M_ * 512);     // M*256 sh (no alias)
    short* x1bf   = ctxbf + (size_t)M_ * D_;            // M*256 sh
    short* hbf    = x1bf  + (size_t)M_ * D_;            // M*1024 sh
    short* xbf    = hbf   + (size_t)M_ * FFN_;          // M*256 sh
    short* xlo    = xbf   + (size_t)M_ * D_;
    short* inwbf  = xlo   + (size_t)M_ * D_;
    short* outwbf = inwbf + (size_t)768 * D_;
    short* w1bf   = outwbf + (size_t)D_ * D_;
    short* w2bf   = w1bf  + (size_t)FFN_ * D_;
    short* wqh    = w2bf  + (size_t)D_ * FFN_;
    short* wql    = wqh + (size_t)RD_ * D_;
    short* wkh    = wql + (size_t)RD_ * D_;
    short* wkl    = wkh + (size_t)RD_ * D_;

    dim3 blk(256);

    // 0) all bf16 conversions (+ hi/lo splits), one launch
    convert_all_kernel<<<dim3((N8_ALL + 255) / 256), blk, 0, stream>>>(
        x, in_w, out_w, w1, w2, wq_rec, wk_rec,
        xbf, xlo, inwbf, outwbf, w1bf, w2bf, wqh, wql, wkh, wkl);

    // 1) qkv = x @ in_proj_w^T + b  (MFMA, bf16 out, 64x128 -> 768 blocks)
    gemm_mfma<64, 128, 1, 0><<<dim3(768 / 128, M_ / 64), blk, 0, stream>>>(xbf, inwbf, in_b, qkvbf, M_, 768, D_);
    // 2) xq/xk projections, split-bf16 MFMA -> qh/ql/kh/kl (512 blocks)
    xqk_mfma<<<dim3(RD_ / 64, M_ / 64, 2), blk, 0, stream>>>(
        xbf, xlo, wqh, wql, wkh, wkl, qh, ql, kh, kl);
    // 3) logits, split-bf16 MFMA (1024 blocks)
    logits_mfma<<<dim3(C_ / 64, C_ / 64, B_), blk, 0, stream>>>(qh, ql, kh, kl, logits);
    // 4) fused top-16 + gathered attention -> ctx (bf16)
    topk_attn_kernel<<<dim3(M_ / 4), blk, 0, stream>>>(logits, qkvbf, ctxbf);
    // 5) out projection + add + LN1 (fused) -> x1 fp32 + x1bf
    gemm_ln_mfma<256, 1><<<dim3(M_ / 32), blk, 0, stream>>>(
        ctxbf, outwbf, out_b, x, ln1_g, ln1_b, x1, x1bf);
    // 6) h = gelu(x1 @ w1^T + b1) (MFMA, 128x128 -> 512 blocks, bf16 out)
    gemm_mfma<128, 128, 1, 1><<<dim3(FFN_ / 128, M_ / 128), blk, 0, stream>>>(x1bf, w1bf, b1, hbf, M_, FFN_, D_);
    // 7) y = h @ w2^T + b2 + x1, LN2 (fused) -> out
    gemm_ln_mfma<1024, 0><<<dim3(M_ / 32), blk, 0, stream>>>(
        hbf, w2bf, b2, x1, ln2_g, ln2_b, out, nullptr);
}

// Round 11
// 106.293 us; speedup vs baseline: 1.4324x; 1.1583x over previous
//
#include <hip/hip_runtime.h>
#include <hip/hip_bf16.h>
#include <math.h>

#define B_   16
#define C_   512
#define D_   256
#define K_   16
#define RD_  128
#define H_   8
#define HD_  32
#define FFN_ 1024
#define M_   (B_ * C_)   // 8192 rows

typedef __attribute__((ext_vector_type(8))) short bf16x8;
typedef __attribute__((ext_vector_type(4))) float f32x4;

typedef __attribute__((address_space(1))) const int ga_int;
typedef __attribute__((address_space(3))) int ls_int;

static __device__ __forceinline__ short f2bf(float v) {
    __hip_bfloat16 h = __float2bfloat16(v);
    return *(short*)&h;
}
static __device__ __forceinline__ float bf2f(short s) {
    __hip_bfloat16 h = *(__hip_bfloat16*)&s;
    return __bfloat162float(h);
}
static __device__ __forceinline__ float4 ld4bf(const short* p) {
    uint2 u = *(const uint2*)p;
    float4 r;
    r.x = __uint_as_float((u.x & 0xffffu) << 16);
    r.y = __uint_as_float(u.x & 0xffff0000u);
    r.z = __uint_as_float((u.y & 0xffffu) << 16);
    r.w = __uint_as_float(u.y & 0xffff0000u);
    return r;
}

// ---------------------------------------------------------------------------
// All fp32->bf16 conversions in ONE kernel. x emits HI+LO; wq/wk emit HI+LO.
// ---------------------------------------------------------------------------
#define N8_X    (M_ * D_ / 8)
#define N8_INW  (768 * D_ / 8)
#define N8_OUTW (D_ * D_ / 8)
#define N8_W1   (FFN_ * D_ / 8)
#define N8_W2   (D_ * FFN_ / 8)
#define N8_WQ   (RD_ * D_ / 8)
#define N8_ALL  (N8_X + N8_INW + N8_OUTW + N8_W1 + N8_W2 + 2 * N8_WQ)

__global__ __launch_bounds__(256) void convert_all_kernel(
    const float* __restrict__ x, const float* __restrict__ inw,
    const float* __restrict__ outw, const float* __restrict__ w1,
    const float* __restrict__ w2, const float* __restrict__ wq,
    const float* __restrict__ wk,
    short* __restrict__ xbf, short* __restrict__ xlo,
    short* __restrict__ inwbf, short* __restrict__ outwbf,
    short* __restrict__ w1bf, short* __restrict__ w2bf,
    short* __restrict__ wqh, short* __restrict__ wql,
    short* __restrict__ wkh, short* __restrict__ wkl)
{
    int i = blockIdx.x * 256 + threadIdx.x;
    if (i >= N8_ALL) return;

    const float* s; short* dh; short* dl = nullptr; int off;
    if      (i < N8_X)                    { s = x;    dh = xbf;    dl = xlo; off = i; }
    else if (i < N8_X + N8_INW)           { s = inw;  dh = inwbf;  off = i - N8_X; }
    else if (i < N8_X + N8_INW + N8_OUTW) { s = outw; dh = outwbf; off = i - N8_X - N8_INW; }
    else if (i < N8_X + N8_INW + N8_OUTW + N8_W1)
                                          { s = w1;   dh = w1bf;   off = i - N8_X - N8_INW - N8_OUTW; }
    else if (i < N8_X + N8_INW + N8_OUTW + N8_W1 + N8_W2)
                                          { s = w2;   dh = w2bf;   off = i - N8_X - N8_INW - N8_OUTW - N8_W1; }
    else if (i < N8_X + N8_INW + N8_OUTW + N8_W1 + N8_W2 + N8_WQ)
                                          { s = wq;   dh = wqh; dl = wql; off = i - N8_X - N8_INW - N8_OUTW - N8_W1 - N8_W2; }
    else                                  { s = wk;   dh = wkh; dl = wkl; off = i - N8_X - N8_INW - N8_OUTW - N8_W1 - N8_W2 - N8_WQ; }

    const float4* sp = (const float4*)s + (size_t)off * 2;
    float4 v0 = sp[0], v1 = sp[1];
    float f[8] = {v0.x, v0.y, v0.z, v0.w, v1.x, v1.y, v1.z, v1.w};
    short rh[8], rl[8];
    #pragma unroll
    for (int j = 0; j < 8; ++j) {
        rh[j] = f2bf(f[j]);
        rl[j] = f2bf(f[j] - bf2f(rh[j]));
    }
    *(bf16x8*)(dh + (size_t)off * 8) = *(bf16x8*)rh;
    if (dl) *(bf16x8*)(dl + (size_t)off * 8) = *(bf16x8*)rl;
}

// ---------------------------------------------------------------------------
// bf16 MFMA GEMM (standalone; used for MLP1). Double-buffered gload_lds.
// ---------------------------------------------------------------------------
template<int BM, int BN, int OUT_BF16, int ACT>
__global__ __launch_bounds__(256) void gemm_mfma(
    const short* __restrict__ A, const short* __restrict__ W,
    const float* __restrict__ bias, void* __restrict__ Cout,
    int M, int N, int Kd)
{
    __shared__ short As[2][BM * 32];
    __shared__ short Bs[2][BN * 32];
    const int tid  = threadIdx.x;
    const int wave = tid >> 6;
    const int lane = tid & 63;
    const int bm = blockIdx.y * BM;
    const int bn = blockIdx.x * BN;
    constexpr int MI = BM / 32;
    constexpr int NJ = BN / 32;
    const int wr = (wave >> 1) * (BM / 2);
    const int wc = (wave & 1) * (BN / 2);

    const int fr = lane & 15;
    const int fk = (lane >> 4) * 8;
    const int r0 = tid >> 2, ch = (tid & 3) * 8;

    f32x4 acc[MI][NJ];
    #pragma unroll
    for (int i = 0; i < MI; ++i)
        #pragma unroll
        for (int j = 0; j < NJ; ++j)
            acc[i][j] = (f32x4){0.f, 0.f, 0.f, 0.f};

    auto stage = [&](int buf, int k0) {
        #pragma unroll
        for (int i = 0; i < BM / 64; ++i)
            __builtin_amdgcn_global_load_lds(
                (ga_int*)&A[(size_t)(bm + r0 + i * 64) * Kd + k0 + ch],
                (ls_int*)&As[buf][(tid + i * 256) * 8], 16, 0, 0);
        #pragma unroll
        for (int j = 0; j < BN / 64; ++j)
            __builtin_amdgcn_global_load_lds(
                (ga_int*)&W[(size_t)(bn + r0 + j * 64) * Kd + k0 + ch],
                (ls_int*)&Bs[buf][(tid + j * 256) * 8], 16, 0, 0);
    };

    stage(0, 0);
    int cur = 0;

    for (int k0 = 0; k0 < Kd; k0 += 32) {
        __syncthreads();
        if (k0 + 32 < Kd) stage(cur ^ 1, k0 + 32);

        bf16x8 af[MI], bfr[NJ];
        #pragma unroll
        for (int i = 0; i < MI; ++i) af[i]  = *(bf16x8*)&As[cur][(wr + i * 16 + fr) * 32 + fk];
        #pragma unroll
        for (int j = 0; j < NJ; ++j) bfr[j] = *(bf16x8*)&Bs[cur][(wc + j * 16 + fr) * 32 + fk];
        #pragma unroll
        for (int i = 0; i < MI; ++i)
            #pragma unroll
            for (int j = 0; j < NJ; ++j)
                acc[i][j] = __builtin_amdgcn_mfma_f32_16x16x32_bf16(af[i], bfr[j], acc[i][j], 0, 0, 0);
        cur ^= 1;
    }

    const int rowbase = (lane >> 4) * 4;
    #pragma unroll
    for (int i = 0; i < MI; ++i) {
        #pragma unroll
        for (int j = 0; j < NJ; ++j) {
            const int n = bn + wc + j * 16 + fr;
            const float bn_v = bias ? bias[n] : 0.f;
            #pragma unroll
            for (int r = 0; r < 4; ++r) {
                const int m = bm + wr + i * 16 + rowbase + r;
                float v = acc[i][j][r] + bn_v;
                if (ACT) v = 0.5f * v * (1.0f + erff(v * 0.70710678118654752f));
                if (OUT_BF16) ((short*)Cout)[(size_t)m * N + n] = f2bf(v);
                else          ((float*)Cout)[(size_t)m * N + n] = v;
            }
        }
    }
}

// ---------------------------------------------------------------------------
// MERGED projection kernel: blocks 0..767 compute qkv (64x128 tile, bf16 out),
// blocks 768..1279 compute xq/xk split-bf16 (64x64 tile, hi/lo out).
// Both paths carve one 24KB smem arena; independent, so one launch.
// ---------------------------------------------------------------------------
__global__ __launch_bounds__(256) void proj_kernel(
    const short* __restrict__ xbf, const short* __restrict__ xlo,
    const short* __restrict__ inwbf, const float* __restrict__ in_b,
    const short* __restrict__ wqh, const short* __restrict__ wql,
    const short* __restrict__ wkh, const short* __restrict__ wkl,
    short* __restrict__ qkvbf,
    short* __restrict__ qh, short* __restrict__ ql,
    short* __restrict__ kh, short* __restrict__ kl)
{
    __shared__ short smem[12288];   // 24 KB arena
    const int bid  = blockIdx.x;
    const int tid  = threadIdx.x;
    const int wave = tid >> 6;
    const int lane = tid & 63;
    const int fr = lane & 15;
    const int fk = (lane >> 4) * 8;
    const int r0 = tid >> 2, ch = (tid & 3) * 8;

    if (bid < 768) {
        // ---- qkv path: BM=64, BN=128, Kd=256, double-buffered ----
        const int bm = (bid / 6) * 64;
        const int bn = (bid % 6) * 128;
        const int wr = (wave >> 1) * 32;
        const int wc = (wave & 1) * 64;
        short* As = smem;            // 2 bufs x 2048
        short* Bs = smem + 4096;     // 2 bufs x 4096

        f32x4 acc[2][4];
        #pragma unroll
        for (int i = 0; i < 2; ++i)
            #pragma unroll
            for (int j = 0; j < 4; ++j)
                acc[i][j] = (f32x4){0.f, 0.f, 0.f, 0.f};

        auto stage = [&](int buf, int k0) {
            __builtin_amdgcn_global_load_lds(
                (ga_int*)&xbf[(size_t)(bm + r0) * D_ + k0 + ch],
                (ls_int*)&As[buf * 2048 + tid * 8], 16, 0, 0);
            #pragma unroll
            for (int j = 0; j < 2; ++j)
                __builtin_amdgcn_global_load_lds(
                    (ga_int*)&inwbf[(size_t)(bn + r0 + j * 64) * D_ + k0 + ch],
                    (ls_int*)&Bs[buf * 4096 + (tid + j * 256) * 8], 16, 0, 0);
        };

        stage(0, 0);
        int cur = 0;
        for (int k0 = 0; k0 < D_; k0 += 32) {
            __syncthreads();
            if (k0 + 32 < D_) stage(cur ^ 1, k0 + 32);
            bf16x8 af[2], bfr[4];
            #pragma unroll
            for (int i = 0; i < 2; ++i) af[i]  = *(bf16x8*)&As[cur * 2048 + (wr + i * 16 + fr) * 32 + fk];
            #pragma unroll
            for (int j = 0; j < 4; ++j) bfr[j] = *(bf16x8*)&Bs[cur * 4096 + (wc + j * 16 + fr) * 32 + fk];
            #pragma unroll
            for (int i = 0; i < 2; ++i)
                #pragma unroll
                for (int j = 0; j < 4; ++j)
                    acc[i][j] = __builtin_amdgcn_mfma_f32_16x16x32_bf16(af[i], bfr[j], acc[i][j], 0, 0, 0);
            cur ^= 1;
        }

        const int rowbase = (lane >> 4) * 4;
        #pragma unroll
        for (int i = 0; i < 2; ++i)
            #pragma unroll
            for (int j = 0; j < 4; ++j) {
                const int n = bn + wc + j * 16 + fr;
                const float bv = in_b[n];
                #pragma unroll
                for (int r = 0; r < 4; ++r) {
                    const int m = bm + wr + i * 16 + rowbase + r;
                    qkvbf[(size_t)m * 768 + n] = f2bf(acc[i][j][r] + bv);
                }
            }
    } else {
        // ---- xq/xk split-bf16 path: 64x64 tile, Kd=256 ----
        const int t = bid - 768;
        const int z = t >> 8;            // 0 = q, 1 = k
        const int rem = t & 255;
        const int bm = (rem >> 1) * 64;
        const int bn = (rem & 1) * 64;
        const short* Wh = z ? wkh : wqh;
        const short* Wl = z ? wkl : wql;
        short* Oh = z ? kh : qh;
        short* Ol = z ? kl : ql;
        short* Ah = smem;          // 2048 each
        short* Al = smem + 2048;
        short* Bh = smem + 4096;
        short* Bl = smem + 6144;

        const int wr = (wave >> 1) * 32;
        const int wc = (wave & 1) * 32;

        f32x4 acc[2][2];
        #pragma unroll
        for (int i = 0; i < 2; ++i)
            #pragma unroll
            for (int j = 0; j < 2; ++j)
                acc[i][j] = (f32x4){0.f, 0.f, 0.f, 0.f};

        for (int k0 = 0; k0 < D_; k0 += 32) {
            __builtin_amdgcn_global_load_lds((ga_int*)&xbf[(size_t)(bm + r0) * D_ + k0 + ch], (ls_int*)&Ah[tid * 8], 16, 0, 0);
            __builtin_amdgcn_global_load_lds((ga_int*)&xlo[(size_t)(bm + r0) * D_ + k0 + ch], (ls_int*)&Al[tid * 8], 16, 0, 0);
            __builtin_amdgcn_global_load_lds((ga_int*)&Wh[(size_t)(bn + r0) * D_ + k0 + ch], (ls_int*)&Bh[tid * 8], 16, 0, 0);
            __builtin_amdgcn_global_load_lds((ga_int*)&Wl[(size_t)(bn + r0) * D_ + k0 + ch], (ls_int*)&Bl[tid * 8], 16, 0, 0);
            __syncthreads();

            bf16x8 ah[2], al[2], bh[2], bl[2];
            #pragma unroll
            for (int i = 0; i < 2; ++i) {
                ah[i] = *(bf16x8*)&Ah[(wr + i * 16 + fr) * 32 + fk];
                al[i] = *(bf16x8*)&Al[(wr + i * 16 + fr) * 32 + fk];
            }
            #pragma unroll
            for (int j = 0; j < 2; ++j) {
                bh[j] = *(bf16x8*)&Bh[(wc + j * 16 + fr) * 32 + fk];
                bl[j] = *(bf16x8*)&Bl[(wc + j * 16 + fr) * 32 + fk];
            }
            #pragma unroll
            for (int i = 0; i < 2; ++i)
                #pragma unroll
                for (int j = 0; j < 2; ++j) {
                    acc[i][j] = __builtin_amdgcn_mfma_f32_16x16x32_bf16(ah[i], bh[j], acc[i][j], 0, 0, 0);
                    acc[i][j] = __builtin_amdgcn_mfma_f32_16x16x32_bf16(ah[i], bl[j], acc[i][j], 0, 0, 0);
                    acc[i][j] = __builtin_amdgcn_mfma_f32_16x16x32_bf16(al[i], bh[j], acc[i][j], 0, 0, 0);
                }
            __syncthreads();
        }

        const int rowbase = (lane >> 4) * 4;
        #pragma unroll
        for (int i = 0; i < 2; ++i)
            #pragma unroll
            for (int j = 0; j < 2; ++j) {
                const int n = bn + wc + j * 16 + fr;
                #pragma unroll
                for (int r = 0; r < 4; ++r) {
                    const int m = bm + wr + i * 16 + rowbase + r;
                    float v = acc[i][j][r];
                    short h = f2bf(v);
                    Oh[(size_t)m * RD_ + n] = h;
                    Ol[(size_t)m * RD_ + n] = f2bf(v - bf2f(h));
                }
            }
    }
}

// ---------------------------------------------------------------------------
// Split-bf16 MFMA logits: logits[b,q,c] = qh.kh + qh.kl + ql.kh (fp32 out).
// ---------------------------------------------------------------------------
__global__ __launch_bounds__(256) void logits_mfma(
    const short* __restrict__ qh, const short* __restrict__ ql,
    const short* __restrict__ kh, const short* __restrict__ kl,
    float* __restrict__ out)
{
    __shared__ short Ah[64 * 32], Al[64 * 32], Bh[64 * 32], Bl[64 * 32];
    const int tid  = threadIdx.x;
    const int wave = tid >> 6;
    const int lane = tid & 63;
    const int base = blockIdx.z * C_;
    const int bm = blockIdx.y * 64;
    const int bn = blockIdx.x * 64;
    const int wr = (wave >> 1) * 32;
    const int wc = (wave & 1) * 32;
    const int fr = lane & 15;
    const int fk = (lane >> 4) * 8;
    const int r0 = tid >> 2, ch = (tid & 3) * 8;

    f32x4 acc[2][2];
    #pragma unroll
    for (int i = 0; i < 2; ++i)
        #pragma unroll
        for (int j = 0; j < 2; ++j)
            acc[i][j] = (f32x4){0.f, 0.f, 0.f, 0.f};

    for (int k0 = 0; k0 < RD_; k0 += 32) {
        __builtin_amdgcn_global_load_lds((ga_int*)&qh[(size_t)(base + bm + r0) * RD_ + k0 + ch], (ls_int*)&Ah[tid * 8], 16, 0, 0);
        __builtin_amdgcn_global_load_lds((ga_int*)&ql[(size_t)(base + bm + r0) * RD_ + k0 + ch], (ls_int*)&Al[tid * 8], 16, 0, 0);
        __builtin_amdgcn_global_load_lds((ga_int*)&kh[(size_t)(base + bn + r0) * RD_ + k0 + ch], (ls_int*)&Bh[tid * 8], 16, 0, 0);
        __builtin_amdgcn_global_load_lds((ga_int*)&kl[(size_t)(base + bn + r0) * RD_ + k0 + ch], (ls_int*)&Bl[tid * 8], 16, 0, 0);
        __syncthreads();

        bf16x8 ah[2], al[2], bh[2], bl[2];
        #pragma unroll
        for (int i = 0; i < 2; ++i) {
            ah[i] = *(bf16x8*)&Ah[(wr + i * 16 + fr) * 32 + fk];
            al[i] = *(bf16x8*)&Al[(wr + i * 16 + fr) * 32 + fk];
        }
        #pragma unroll
        for (int j = 0; j < 2; ++j) {
            bh[j] = *(bf16x8*)&Bh[(wc + j * 16 + fr) * 32 + fk];
            bl[j] = *(bf16x8*)&Bl[(wc + j * 16 + fr) * 32 + fk];
        }
        #pragma unroll
        for (int i = 0; i < 2; ++i)
            #pragma unroll
            for (int j = 0; j < 2; ++j) {
                acc[i][j] = __builtin_amdgcn_mfma_f32_16x16x32_bf16(ah[i], bh[j], acc[i][j], 0, 0, 0);
                acc[i][j] = __builtin_amdgcn_mfma_f32_16x16x32_bf16(ah[i], bl[j], acc[i][j], 0, 0, 0);
                acc[i][j] = __builtin_amdgcn_mfma_f32_16x16x32_bf16(al[i], bh[j], acc[i][j], 0, 0, 0);
            }
        __syncthreads();
    }

    const int rowbase = (lane >> 4) * 4;
    #pragma unroll
    for (int i = 0; i < 2; ++i)
        #pragma unroll
        for (int j = 0; j < 2; ++j) {
            const int n = bn + wc + j * 16 + fr;
            #pragma unroll
            for (int r = 0; r < 4; ++r) {
                const int m = base + bm + wr + i * 16 + rowbase + r;
                out[(size_t)m * C_ + n] = acc[i][j][r];
            }
        }
}

// ---------------------------------------------------------------------------
// FUSED top-16 + attention, ONE WAVE per (b,q) row. f32 fmax butterfly +
// ballot selection (same lowest-index tie semantics as jax.lax.top_k).
// ---------------------------------------------------------------------------
__global__ __launch_bounds__(256) void topk_attn_kernel(
    const float* __restrict__ logits, const short* __restrict__ qkv,
    short* __restrict__ ctxbf)
{
    const int wave = threadIdx.x >> 6;
    const int lane = threadIdx.x & 63;
    const int row  = blockIdx.x * 4 + wave;
    const int bbase = row & ~(C_ - 1);

    // ---- top-16 ----
    const float* lrow = logits + (size_t)row * C_;
    float v[8];
    #pragma unroll
    for (int j = 0; j < 8; ++j) v[j] = lrow[lane * 8 + j];

    int ii[K_];
    #pragma unroll
    for (int sel = 0; sel < K_; ++sel) {
        float bv = v[0]; int bj = 0;
        #pragma unroll
        for (int j = 1; j < 8; ++j)
            if (v[j] > bv) { bv = v[j]; bj = j; }     // strict > : lowest j on ties
        float wb = bv;
        #pragma unroll
        for (int s = 1; s < 64; s <<= 1)
            wb = fmaxf(wb, __shfl_xor(wb, s, 64));
        unsigned long long mask = __ballot(bv == wb);
        int wl = __ffsll(mask) - 1;                    // lowest lane = lowest index
        int wj = __shfl(bj, wl, 64);
        ii[sel] = wl * 8 + wj;
        #pragma unroll
        for (int j = 0; j < 8; ++j)
            if (lane == wl && bj == j) v[j] = -INFINITY;
    }

    // ---- attention over the 16 selected slots (bf16 loads, fp32 math) ----
    const short* qrow = qkv + (size_t)row * 768;
    float4 qv = ld4bf(qrow + lane * 4);

    float s[K_];
    #pragma unroll
    for (int k = 0; k < K_; ++k) {
        float4 kv = ld4bf(qkv + (size_t)(bbase + ii[k]) * 768 + 256 + lane * 4);
        float p = qv.x * kv.x + qv.y * kv.y + qv.z * kv.z + qv.w * kv.w;
        p += __shfl_xor(p, 1, 64);
        p += __shfl_xor(p, 2, 64);
        p += __shfl_xor(p, 4, 64);
        s[k] = p * 0.17677669529663687f;
    }

    float m = s[0];
    #pragma unroll
    for (int k = 1; k < K_; ++k) m = fmaxf(m, s[k]);
    float ssum = 0.f;
    #pragma unroll
    for (int k = 0; k < K_; ++k) { s[k] = __expf(s[k] - m); ssum += s[k]; }
    const float inv = 1.f / ssum;

    float4 acc = {0.f, 0.f, 0.f, 0.f};
    #pragma unroll
    for (int k = 0; k < K_; ++k) {
        float4 vvv = ld4bf(qkv + (size_t)(bbase + ii[k]) * 768 + 512 + lane * 4);
        float w = s[k] * inv;
        acc.x += w * vvv.x; acc.y += w * vvv.y; acc.z += w * vvv.z; acc.w += w * vvv.w;
    }

    unsigned lo = (unsigned)(unsigned short)f2bf(acc.x) | ((unsigned)(unsigned short)f2bf(acc.y) << 16);
    unsigned hi = (unsigned)(unsigned short)f2bf(acc.z) | ((unsigned)(unsigned short)f2bf(acc.w) << 16);
    uint2 pk = {lo, hi};
    *(uint2*)(ctxbf + (size_t)row * D_ + lane * 4) = pk;
}

// ---------------------------------------------------------------------------
// FUSED GEMM + bias + residual + LayerNorm. BM=16, BN=256 (full row),
// grid M/16 = 512 -> 2 blocks/CU. 4 waves tile N; cross-wave LN via LDS.
// ---------------------------------------------------------------------------
template<int KD, int WBF>
__global__ __launch_bounds__(256) void gemm_ln_mfma(
    const short* __restrict__ A, const short* __restrict__ W,
    const float* __restrict__ bias, const float* __restrict__ res,
    const float* __restrict__ g, const float* __restrict__ beta,
    float* __restrict__ out, short* __restrict__ outbf)
{
    __shared__ short As[2][16 * 32];
    __shared__ short Bs[2][256 * 32];
    __shared__ float part[4][16][2];

    const int tid  = threadIdx.x;
    const int wave = tid >> 6;
    const int lane = tid & 63;
    const int bm = blockIdx.x * 16;
    const int wc = wave * 64;
    const int fr = lane & 15;
    const int fk = (lane >> 4) * 8;
    const int r0 = tid >> 2, ch = (tid & 3) * 8;

    f32x4 acc[4];
    #pragma unroll
    for (int j = 0; j < 4; ++j) acc[j] = (f32x4){0.f, 0.f, 0.f, 0.f};

    auto stage = [&](int buf, int k0) {
        if (tid < 64)
            __builtin_amdgcn_global_load_lds(
                (ga_int*)&A[(size_t)(bm + r0) * KD + k0 + ch],
                (ls_int*)&As[buf][tid * 8], 16, 0, 0);
        #pragma unroll
        for (int j = 0; j < 4; ++j)
            __builtin_amdgcn_global_load_lds(
                (ga_int*)&W[(size_t)(r0 + j * 64) * KD + k0 + ch],
                (ls_int*)&Bs[buf][(tid + j * 256) * 8], 16, 0, 0);
    };

    stage(0, 0);
    int cur = 0;

    for (int k0 = 0; k0 < KD; k0 += 32) {
        __syncthreads();
        if (k0 + 32 < KD) stage(cur ^ 1, k0 + 32);

        bf16x8 af = *(bf16x8*)&As[cur][fr * 32 + fk];
        bf16x8 bfr[4];
        #pragma unroll
        for (int j = 0; j < 4; ++j) bfr[j] = *(bf16x8*)&Bs[cur][(wc + j * 16 + fr) * 32 + fk];
        #pragma unroll
        for (int j = 0; j < 4; ++j)
            acc[j] = __builtin_amdgcn_mfma_f32_16x16x32_bf16(af, bfr[j], acc[j], 0, 0, 0);
        cur ^= 1;
    }

    // ---- epilogue: v = acc + bias + res; row-wise LN over 256 cols ----
    const int rowbase = (lane >> 4) * 4;
    float vv[4][4];
    float sum[4] = {0.f, 0.f, 0.f, 0.f};
    float sq[4]  = {0.f, 0.f, 0.f, 0.f};

    #pragma unroll
    for (int j = 0; j < 4; ++j) {
        const int n = wc + j * 16 + fr;
        const float bv = bias[n];
        #pragma unroll
        for (int r = 0; r < 4; ++r) {
            const int m = bm + rowbase + r;
            float v = acc[j][r] + bv + res[(size_t)m * D_ + n];
            vv[j][r] = v;
            sum[r] += v;
            sq[r]  += v * v;
        }
    }

    #pragma unroll
    for (int r = 0; r < 4; ++r)
        #pragma unroll
        for (int s = 1; s < 16; s <<= 1) {
            sum[r] += __shfl_xor(sum[r], s, 64);
            sq[r]  += __shfl_xor(sq[r],  s, 64);
        }

    if (fr == 0) {
        #pragma unroll
        for (int r = 0; r < 4; ++r) {
            part[wave][rowbase + r][0] = sum[r];
            part[wave][rowbase + r][1] = sq[r];
        }
    }
    __syncthreads();

    #pragma unroll
    for (int r = 0; r < 4; ++r) {
        const int ml = rowbase + r;
        const float S = part[0][ml][0] + part[1][ml][0] + part[2][ml][0] + part[3][ml][0];
        const float Q = part[0][ml][1] + part[1][ml][1] + part[2][ml][1] + part[3][ml][1];
        const float mean = S * (1.0f / D_);
        const float var  = Q * (1.0f / D_) - mean * mean;
        const float rstd = rsqrtf(var + 1e-5f);
        const int m = bm + ml;
        #pragma unroll
        for (int j = 0; j < 4; ++j) {
            const int n = wc + j * 16 + fr;
            float o = (vv[j][r] - mean) * rstd * g[n] + beta[n];
            out[(size_t)m * D_ + n] = o;
            if (WBF) outbf[(size_t)m * D_ + n] = f2bf(o);
        }
    }
}

// ---------------------------------------------------------------------------
extern "C" void kernel_launch(void* const* d_in, const int* in_sizes, int n_in,
                              void* d_out, int out_size, void* d_ws, size_t ws_size,
                              hipStream_t stream)
{
    const float* x      = (const float*)d_in[0];
    const float* wq_rec = (const float*)d_in[1];
    const float* wk_rec = (const float*)d_in[2];
    const float* in_w   = (const float*)d_in[3];
    const float* in_b   = (const float*)d_in[4];
    const float* out_w  = (const float*)d_in[5];
    const float* out_b  = (const float*)d_in[6];
    const float* ln1_g  = (const float*)d_in[7];
    const float* ln1_b  = (const float*)d_in[8];
    const float* w1     = (const float*)d_in[9];
    const float* b1     = (const float*)d_in[10];
    const float* w2     = (const float*)d_in[11];
    const float* b2     = (const float*)d_in[12];
    const float* ln2_g  = (const float*)d_in[13];
    const float* ln2_b  = (const float*)d_in[14];
    float* out = (float*)d_out;

    // ---- workspace layout ----
    short* qkvbf = (short*)d_ws;                    // M*768 sh (bf16 q|k|v)
    short* qh    = qkvbf + (size_t)M_ * 768;        // M*128 sh
    short* ql    = qh + (size_t)M_ * RD_;
    short* kh    = ql + (size_t)M_ * RD_;
    short* kl    = kh + (size_t)M_ * RD_;
    float* x1    = (float*)(kl + (size_t)M_ * RD_); // M*256 f
    float* U     = x1 + (size_t)M_ * D_;
    float* logits = U;                                  // M*512 f
    short* ctxbf  = (short*)(U + (size_t)M_ * 512);     // M*256 sh
    short* x1bf   = ctxbf + (size_t)M_ * D_;            // M*256 sh
    short* hbf    = x1bf  + (size_t)M_ * D_;            // M*1024 sh
    short* xbf    = hbf   + (size_t)M_ * FFN_;          // M*256 sh
    short* xlo    = xbf   + (size_t)M_ * D_;
    short* inwbf  = xlo   + (size_t)M_ * D_;
    short* outwbf = inwbf + (size_t)768 * D_;
    short* w1bf   = outwbf + (size_t)D_ * D_;
    short* w2bf   = w1bf  + (size_t)FFN_ * D_;
    short* wqh    = w2bf  + (size_t)D_ * FFN_;
    short* wql    = wqh + (size_t)RD_ * D_;
    short* wkh    = wql + (size_t)RD_ * D_;
    short* wkl    = wkh + (size_t)RD_ * D_;

    dim3 blk(256);

    // 0) all bf16 conversions (+ hi/lo splits), one launch
    convert_all_kernel<<<dim3((N8_ALL + 255) / 256), blk, 0, stream>>>(
        x, in_w, out_w, w1, w2, wq_rec, wk_rec,
        xbf, xlo, inwbf, outwbf, w1bf, w2bf, wqh, wql, wkh, wkl);

    // 1) merged qkv + xq/xk projections (1280 blocks)
    proj_kernel<<<dim3(1280), blk, 0, stream>>>(
        xbf, xlo, inwbf, in_b, wqh, wql, wkh, wkl, qkvbf, qh, ql, kh, kl);
    // 2) logits, split-bf16 MFMA (1024 blocks)
    logits_mfma<<<dim3(C_ / 64, C_ / 64, B_), blk, 0, stream>>>(qh, ql, kh, kl, logits);
    // 3) fused top-16 + gathered attention -> ctx (bf16)
    topk_attn_kernel<<<dim3(M_ / 4), blk, 0, stream>>>(logits, qkvbf, ctxbf);
    // 4) out projection + add + LN1 (fused, BM=16 -> 512 blocks)
    gemm_ln_mfma<256, 1><<<dim3(M_ / 16), blk, 0, stream>>>(
        ctxbf, outwbf, out_b, x, ln1_g, ln1_b, x1, x1bf);
    // 5) h = gelu(x1 @ w1^T + b1) (MFMA, 64x128 -> 1024 blocks, bf16 out)
    gemm_mfma<64, 128, 1, 1><<<dim3(FFN_ / 128, M_ / 64), blk, 0, stream>>>(x1bf, w1bf, b1, hbf, M_, FFN_, D_);
    // 6) y = h @ w2^T + b2 + x1, LN2 (fused, BM=16 -> 512 blocks)
    gemm_ln_mfma<1024, 0><<<dim3(M_ / 16), blk, 0, stream>>>(
        hbf, w2bf, b2, x1, ln2_g, ln2_b, out, nullptr);
}